// Round 13
// baseline (607.571 us; speedup 1.0000x reference)
//
#include <hip/hip_runtime.h>
#include <hip/hip_bf16.h>
#include <math.h>

#define KCL 2048
#define LRELU_NEG 0.01f
#define EPSBN 1e-5f
#define OSTR 72   // padded LDS row stride (ushorts); 144B rows, 16B-aligned

using s8v = __attribute__((ext_vector_type(8))) short;   // 8 bf16 (4 VGPRs)
using f4v = __attribute__((ext_vector_type(4))) float;   // MFMA accumulator

union U8 { ushort u[8]; uint4 v; };

__device__ __forceinline__ float lrelu(float x) { return x > 0.f ? x : LRELU_NEG * x; }
__device__ __forceinline__ ushort f2bf(float f) {
    __hip_bfloat16 h = __float2bfloat16(f);
    return *reinterpret_cast<ushort*>(&h);
}
__device__ __forceinline__ float bf2f(ushort u) { return __uint_as_float(((unsigned)u) << 16); }

__device__ __forceinline__ unsigned encf(float f) {
    unsigned u = __float_as_uint(f);
    return (u & 0x80000000u) ? ~u : (u | 0x80000000u);
}
__device__ __forceinline__ float decf(unsigned u) {
    return __uint_as_float((u & 0x80000000u) ? (u & 0x7fffffffu) : ~u);
}

// finalize BN stats into LDS scale/bias: y = x*sb[col] + sb[64+col]
__device__ __forceinline__ void bn_sb(const double* __restrict__ stats, const float* __restrict__ g,
                                      const float* __restrict__ b, int n, float* sb) {
    int t = threadIdx.x;
    if (t < 64) {
        float mean = (float)(stats[t] / n);
        float ex2 = (float)(stats[64 + t] / n);
        float var = fmaxf(ex2 - mean * mean, 0.f);
        float rstd = rsqrtf(var + EPSBN);
        float sc = rstd * g[t];
        sb[t] = sc;
        sb[64 + t] = b[t] - mean * sc;
    }
    __syncthreads();
}

// MFMA over a staged (swizzled) A tile with B fragments from global (L1/L2-hot).
__device__ __forceinline__ void mfma_tileG(const uint4* As, const ushort* Wmat, int ws, int koff,
                                           int rowA0, int rowA1, int swA0, int swA1,
                                           int l15, int lg, f4v acc[2][4]) {
    const s8v* Av = (const s8v*)As;
#pragma unroll
    for (int kb = 0; kb < 2; ++kb) {
        int gch = kb * 4 + lg;
        s8v a0 = Av[rowA0 * 8 + (gch ^ swA0)];
        s8v a1 = Av[rowA1 * 8 + (gch ^ swA1)];
#pragma unroll
        for (int nf = 0; nf < 4; ++nf) {
            int col = nf * 16 + l15;
            s8v bf = *(const s8v*)(Wmat + (size_t)col * ws + koff + gch * 8);
            acc[0][nf] = __builtin_amdgcn_mfma_f32_16x16x32_bf16(a0, bf, acc[0][nf], 0, 0, 0);
            acc[1][nf] = __builtin_amdgcn_mfma_f32_16x16x32_bf16(a1, bf, acc[1][nf], 0, 0, 0);
        }
    }
}

// MFMA with A-operand fragments read DIRECTLY from the padded row-major ost tile
// (row r's K is contiguous at ost + r*OSTR; 16B-aligned since OSTR*2 = 144 = 9*16).
__device__ __forceinline__ void mfma_tileOst(const ushort* ost, const ushort* Wmat,
                                             int rowA0, int rowA1, int l15, int lg, f4v acc[2][4]) {
#pragma unroll
    for (int kb = 0; kb < 2; ++kb) {
        int gch = kb * 4 + lg;
        s8v a0 = *(const s8v*)(ost + rowA0 * OSTR + gch * 8);
        s8v a1 = *(const s8v*)(ost + rowA1 * OSTR + gch * 8);
#pragma unroll
        for (int nf = 0; nf < 4; ++nf) {
            int col = nf * 16 + l15;
            s8v bf = *(const s8v*)(Wmat + (size_t)col * 64 + gch * 8);
            acc[0][nf] = __builtin_amdgcn_mfma_f32_16x16x32_bf16(a0, bf, acc[0][nf], 0, 0, 0);
            acc[1][nf] = __builtin_amdgcn_mfma_f32_16x16x32_bf16(a1, bf, acc[1][nf], 0, 0, 0);
        }
    }
}

__device__ __forceinline__ void stage_a_bf16(const ushort* S, uint4* As, int row, int n, int arow, int ah) {
    uint4 c0 = {0, 0, 0, 0}, c1 = c0, c2 = c0, c3 = c0;
    if (row < n) {
        const uint4* s = (const uint4*)(S + (size_t)row * 64) + ah * 4;
        c0 = s[0]; c1 = s[1]; c2 = s[2]; c3 = s[3];
    }
    int sw = arow & 7;
    uint4* dst = As + arow * 8;
    dst[(ah * 4 + 0) ^ sw] = c0;
    dst[(ah * 4 + 1) ^ sw] = c1;
    dst[(ah * 4 + 2) ^ sw] = c2;
    dst[(ah * 4 + 3) ^ sw] = c3;
}

// gather-stage by explicit index (gi < 0 -> zero row)
__device__ __forceinline__ void stage_a_gather(const ushort* S, uint4* As, int gi, int arow, int ah) {
    uint4 c0 = {0, 0, 0, 0}, c1 = c0, c2 = c0, c3 = c0;
    if (gi >= 0) {
        const uint4* s = (const uint4*)(S + (size_t)gi * 64) + ah * 4;
        c0 = s[0]; c1 = s[1]; c2 = s[2]; c3 = s[3];
    }
    int sw = arow & 7;
    uint4* dst = As + arow * 8;
    dst[(ah * 4 + 0) ^ sw] = c0;
    dst[(ah * 4 + 1) ^ sw] = c1;
    dst[(ah * 4 + 2) ^ sw] = c2;
    dst[(ah * 4 + 3) ^ sw] = c3;
}

__device__ __forceinline__ void stage_a_vals(const float* vals, uint4* As, int arow, int ah) {
    int sw = arow & 7;
    uint4* dst = As + arow * 8;
#pragma unroll
    for (int c = 0; c < 4; ++c) {
        U8 u;
#pragma unroll
        for (int e = 0; e < 8; ++e) u.u[e] = f2bf(vals[c * 8 + e]);
        dst[(ah * 4 + c) ^ sw] = u.v;
    }
}

// write tile fragments into padded LDS staging (bf16)  [r9-proven]
__device__ __forceinline__ void tile_to_ost(const f4v acc[2][4], ushort* ost, int w, int lane) {
    const int l15 = lane & 15, lg = lane >> 4;
#pragma unroll
    for (int rf = 0; rf < 2; ++rf)
#pragma unroll
        for (int nf = 0; nf < 4; ++nf)
#pragma unroll
            for (int q = 0; q < 4; ++q)
                ost[(w * 32 + rf * 16 + lg * 4 + q) * OSTR + nf * 16 + l15] = f2bf(acc[rf][nf][q]);
}

// same addressing, but apply BN scale/bias + lrelu during the write
__device__ __forceinline__ void tile_to_ost_bn(const f4v acc[2][4], ushort* ost, const float* sb,
                                               int w, int lane) {
    const int l15 = lane & 15, lg = lane >> 4;
#pragma unroll
    for (int rf = 0; rf < 2; ++rf)
#pragma unroll
        for (int nf = 0; nf < 4; ++nf) {
            int col = nf * 16 + l15;
            float sc = sb[col], bi = sb[64 + col];
#pragma unroll
            for (int q = 0; q < 4; ++q)
                ost[(w * 32 + rf * 16 + lg * 4 + q) * OSTR + col] =
                    f2bf(lrelu(acc[rf][nf][q] * sc + bi));
        }
}

// coalesced 64B-per-thread store of the staged tile  [r9-proven]
__device__ __forceinline__ void ost_store(const ushort* ost, ushort* out, int n, int rb, int arow, int ah) {
    int row = rb + arow;
    if (row < n) {
        uint4* dst = (uint4*)(out + (size_t)row * 64 + ah * 32);
        const uint4* src = (const uint4*)(ost + arow * OSTR + ah * 32);
        dst[0] = src[0]; dst[1] = src[1]; dst[2] = src[2]; dst[3] = src[3];
    }
}

// per-tile column stats (sum,sumsq) via shuffle + red[512] floats, atomics to statp
__device__ __forceinline__ void tile_stats(const f4v acc[2][4], float* red, double* statp,
                                           int n, int rb, int w, int lane, int t) {
    const int l15 = lane & 15, lg = lane >> 4;
    int base = rb + w * 32;
#pragma unroll
    for (int nf = 0; nf < 4; ++nf) {
        float s = 0.f, s2 = 0.f;
#pragma unroll
        for (int rf = 0; rf < 2; ++rf)
#pragma unroll
            for (int q = 0; q < 4; ++q) {
                int r = base + rf * 16 + lg * 4 + q;
                if (r < n) {
                    float v = acc[rf][nf][q];
                    s += v;
                    s2 += v * v;
                }
            }
        s += __shfl_xor(s, 16); s += __shfl_xor(s, 32);
        s2 += __shfl_xor(s2, 16); s2 += __shfl_xor(s2, 32);
        if (lg == 0) {
            red[w * 64 + nf * 16 + l15] = s;
            red[256 + w * 64 + nf * 16 + l15] = s2;
        }
    }
}
__device__ __forceinline__ void tile_stats_final(const float* red, double* statp, int t) {
    if (t < 64) {
        float s = red[t] + red[64 + t] + red[128 + t] + red[192 + t];
        float s2 = red[256 + t] + red[320 + t] + red[384 + t] + red[448 + t];
        atomicAdd(&statp[t], (double)s);
        atomicAdd(&statp[64 + t], (double)s2);
    }
}

// ---------------- weight prep: 64 matrices of 64x64, transposed -> bf16 ----------------
__global__ __launch_bounds__(256) void prep_wt64(const float* __restrict__ lw, const float* __restrict__ wW,
                                                 const float* __restrict__ proj, const float* __restrict__ c1,
                                                 const float* __restrict__ c2, ushort* __restrict__ wt) {
    int bk = blockIdx.x;
    const float* W;
    if (bk < 3) W = lw + (size_t)bk * 4096;
    else if (bk < 6) W = wW + (size_t)(bk - 3) * 4096;
    else if (bk < 10) W = proj + (size_t)(bk - 6) * 4096;
    else if (bk < 37) W = c1 + (size_t)(bk - 10) * 4096;
    else W = c2 + (size_t)(bk - 37) * 4096;
    ushort* o = wt + (size_t)bk * 4096;
    for (int i = threadIdx.x; i < 4096; i += 256) {
        int kk = i >> 6, cc = i & 63;
        o[cc * 64 + kk] = f2bf(W[i]);
    }
}

__global__ __launch_bounds__(256) void prep_fuse(const float* __restrict__ Wf, ushort* __restrict__ o) {
    for (int i = threadIdx.x; i < 8192; i += 256) {
        int kk = i >> 6, cc = i & 63;
        o[cc * 128 + kk] = f2bf(Wf[i]);
    }
}

// ---------------- adaptive weights + fp32->bf16 convert ----------------
__global__ __launch_bounds__(256) void adp_cvt_kernel(const float* __restrict__ feat, const float* __restrict__ aW,
                                                      float* __restrict__ adp, ushort* __restrict__ feat16, int n) {
    __shared__ float w[192];
    for (int i = threadIdx.x; i < 192; i += 256) w[i] = aW[i];
    __syncthreads();
    for (long row = (long)blockIdx.x * 256 + threadIdx.x; row < n; row += (long)gridDim.x * 256) {
        const float4* fr = (const float4*)(feat + row * 64);
        ushort4* fo = (ushort4*)(feat16 + row * 64);
        float l0 = 0.f, l1 = 0.f, l2 = 0.f;
#pragma unroll
        for (int q = 0; q < 16; ++q) {
            float4 x = fr[q];
            int k = q * 4;
            l0 += x.x * w[k * 3 + 0] + x.y * w[k * 3 + 3] + x.z * w[k * 3 + 6] + x.w * w[k * 3 + 9];
            l1 += x.x * w[k * 3 + 1] + x.y * w[k * 3 + 4] + x.z * w[k * 3 + 7] + x.w * w[k * 3 + 10];
            l2 += x.x * w[k * 3 + 2] + x.y * w[k * 3 + 5] + x.z * w[k * 3 + 8] + x.w * w[k * 3 + 11];
            ushort4 u;
            u.x = f2bf(x.x); u.y = f2bf(x.y); u.z = f2bf(x.z); u.w = f2bf(x.w);
            fo[q] = u;
        }
        float m = fmaxf(l0, fmaxf(l1, l2));
        float e0 = expf(l0 - m), e1 = expf(l1 - m), e2 = expf(l2 - m);
        float inv = 1.f / (e0 + e1 + e2);
        adp[row * 3 + 0] = e0 * inv;
        adp[row * 3 + 1] = e1 * inv;
        adp[row * 3 + 2] = e2 * inv;
    }
}

// ---------------- cluster histogram, all 3 levels ----------------
__global__ __launch_bounds__(256) void hist3_kernel(const int* __restrict__ clusters, int* __restrict__ cnt,
                                                    int n) {
    __shared__ int h[KCL];
    int l = blockIdx.x % 3;
    int nb = gridDim.x / 3, bi = blockIdx.x / 3;
    for (int i = threadIdx.x; i < KCL; i += 256) h[i] = 0;
    __syncthreads();
    const int* cl = clusters + (size_t)l * n;
    for (long i = (long)bi * 256 + threadIdx.x; i < n; i += (long)nb * 256)
        atomicAdd(&h[cl[i]], 1);
    __syncthreads();
    for (int i = threadIdx.x; i < KCL; i += 256) {
        int v = h[i];
        if (v) atomicAdd(&cnt[l * KCL + i], v);
    }
}

// ---------------- exclusive scan -> absolute offsets + cursor ----------------
__global__ __launch_bounds__(256) void scan_kernel(const int* __restrict__ cnt, int* __restrict__ off,
                                                   int* __restrict__ cursor, int n) {
    int l = blockIdx.x;
    const int* c = cnt + l * KCL;
    __shared__ int part[256];
    __shared__ int pref[256];
    int t = threadIdx.x;
    int base = t * 8;
    int v[8];
    int s = 0;
#pragma unroll
    for (int j = 0; j < 8; ++j) { v[j] = c[base + j]; s += v[j]; }
    part[t] = s;
    __syncthreads();
    if (t == 0) {
        int acc = 0;
        for (int i = 0; i < 256; ++i) { pref[i] = acc; acc += part[i]; }
    }
    __syncthreads();
    int acc = pref[t] + l * n;
#pragma unroll
    for (int j = 0; j < 8; ++j) {
        off[l * KCL + base + j] = acc;
        cursor[l * KCL + base + j] = acc;
        acc += v[j];
    }
}

// ---------------- scatter rows into cluster-sorted perm ----------------
__global__ __launch_bounds__(256) void scatter_kernel(const int* __restrict__ clusters, int* __restrict__ cursor,
                                                      int* __restrict__ perm, int n) {
    long n3 = (long)n * 3;
    for (long i = (long)blockIdx.x * 256 + threadIdx.x; i < n3; i += (long)gridDim.x * 256) {
        int l = (i >= n) + (i >= 2 * (long)n);
        int c = clusters[i];
        int pos = atomicAdd(&cursor[l * KCL + c], 1);
        perm[pos] = (int)(i - (long)l * n);
    }
}

// ================= stats-only mega pass: 7 GEMMs, BN stats, NO output writes =================
__global__ __launch_bounds__(256) void stats7_gemm(const ushort* __restrict__ feat16,
                                                   const ushort* __restrict__ wt64,
                                                   int n, double* __restrict__ stats) {
    __shared__ uint4 As[128 * 8];
    __shared__ float red[512];
    int t = threadIdx.x, lane = t & 63, w = t >> 6;
    int rb = blockIdx.x * 128;
    int arow = t >> 1, ah = t & 1;
    const int l15 = lane & 15, lg = lane >> 4;
    int rowA0 = w * 32 + l15, rowA1 = rowA0 + 16;
    stage_a_bf16(feat16, As, rb + arow, n, arow, ah);
    __syncthreads();
    const int wsl[7] = {0, 1, 2, 6, 7, 8, 9};
    const int ssl[7] = {0, 2, 4, 1, 3, 5, 6};
#pragma unroll
    for (int p = 0; p < 7; ++p) {
        f4v acc[2][4];
#pragma unroll
        for (int rf = 0; rf < 2; ++rf)
#pragma unroll
            for (int nf = 0; nf < 4; ++nf)
#pragma unroll
                for (int q = 0; q < 4; ++q) acc[rf][nf][q] = 0.f;
        mfma_tileG(As, wt64 + (size_t)wsl[p] * 4096, 64, 0, rowA0, rowA1, rowA0 & 7, rowA1 & 7,
                   l15, lg, acc);
        tile_stats(acc, red, stats + (size_t)ssl[p] * 128, n, rb, w, lane, t);
        __syncthreads();
        tile_stats_final(red, stats + (size_t)ssl[p] * 128, t);
        __syncthreads();
    }
}

// ================= meanB: block = (level, cluster); recompute A = gather(feat16) @ lw_l =================
__global__ __launch_bounds__(256) void mean3_fused(const ushort* __restrict__ feat16,
                                                   const ushort* __restrict__ wt64,
                                                   const double* __restrict__ stats,
                                                   const float* __restrict__ lw_g, const float* __restrict__ lw_b,
                                                   int n, const int* __restrict__ cnts,
                                                   const int* __restrict__ offs, const int* __restrict__ perm,
                                                   float* __restrict__ meanB3) {
    int l = blockIdx.x >> 11, c = blockIdx.x & (KCL - 1);
    __shared__ float sb[128];
    __shared__ uint4 As[128 * 8];
    __shared__ float red[256];
    bn_sb(stats + (size_t)(2 * l) * 128, lw_g + l * 64, lw_b + l * 64, n, sb);
    int t = threadIdx.x, lane = t & 63, w = t >> 6;
    int arow = t >> 1, ah = t & 1;
    const int l15 = lane & 15, lg = lane >> 4;
    int rowA0 = w * 32 + l15, rowA1 = rowA0 + 16;
    const ushort* Wm = wt64 + (size_t)l * 4096;
    int o = offs[l * KCL + c], m = cnts[l * KCL + c];
    float colsum[4] = {0.f, 0.f, 0.f, 0.f};
    for (int ch = 0; ch < m; ch += 128) {
        int j = ch + arow;
        int gi = (j < m) ? perm[o + j] : -1;
        __syncthreads();
        stage_a_gather(feat16, As, gi, arow, ah);
        __syncthreads();
        f4v acc[2][4];
#pragma unroll
        for (int rf = 0; rf < 2; ++rf)
#pragma unroll
            for (int nf = 0; nf < 4; ++nf)
#pragma unroll
                for (int q = 0; q < 4; ++q) acc[rf][nf][q] = 0.f;
        mfma_tileG(As, Wm, 64, 0, rowA0, rowA1, rowA0 & 7, rowA1 & 7, l15, lg, acc);
#pragma unroll
        for (int rf = 0; rf < 2; ++rf)
#pragma unroll
            for (int q = 0; q < 4; ++q) {
                int jr = ch + w * 32 + rf * 16 + lg * 4 + q;
                if (jr < m)
#pragma unroll
                    for (int nf = 0; nf < 4; ++nf) {
                        int col = nf * 16 + l15;
                        colsum[nf] += lrelu(acc[rf][nf][q] * sb[col] + sb[64 + col]);
                    }
            }
    }
#pragma unroll
    for (int nf = 0; nf < 4; ++nf) {
        float s = colsum[nf];
        s += __shfl_xor(s, 16); s += __shfl_xor(s, 32);
        if (lg == 0) red[w * 64 + nf * 16 + l15] = s;
    }
    __syncthreads();
    if (t < 64) {
        float s = red[t] + red[64 + t] + red[128 + t] + red[192 + t];
        float cf = (float)m;
        if (cf < 1.f) cf = 1.f;
        meanB3[((size_t)l * KCL + c) * 64 + t] = s / cf;
    }
}

// ================= MW for all 3 levels: meanB_l @ wW_l =================
__global__ __launch_bounds__(256) void mw3_gemm(const float* __restrict__ meanB3, const ushort* __restrict__ wW16,
                                                float* __restrict__ MW3) {
    __shared__ uint4 As[128 * 8];
    int l = blockIdx.x >> 4, b = blockIdx.x & 15;
    const float* src = meanB3 + (size_t)l * KCL * 64;
    float* out = MW3 + (size_t)l * KCL * 64;
    int t = threadIdx.x, lane = t & 63, w = t >> 6;
    int rb = b * 128;
    int arow = t >> 1, ah = t & 1;
    const int l15 = lane & 15, lg = lane >> 4;
    {
        float vals[32];
        const float4* s = (const float4*)(src + (size_t)(rb + arow) * 64 + ah * 32);
#pragma unroll
        for (int q = 0; q < 8; ++q) {
            float4 x = s[q];
            vals[q * 4 + 0] = x.x; vals[q * 4 + 1] = x.y;
            vals[q * 4 + 2] = x.z; vals[q * 4 + 3] = x.w;
        }
        stage_a_vals(vals, As, arow, ah);
    }
    __syncthreads();
    f4v acc[2][4];
#pragma unroll
    for (int rf = 0; rf < 2; ++rf)
#pragma unroll
        for (int nf = 0; nf < 4; ++nf)
#pragma unroll
            for (int q = 0; q < 4; ++q) acc[rf][nf][q] = 0.f;
    int rowA0 = w * 32 + l15, rowA1 = rowA0 + 16;
    mfma_tileG(As, wW16 + (size_t)l * 4096, 64, 0, rowA0, rowA1, rowA0 & 7, rowA1 & 7, l15, lg, acc);
    int base = rb + w * 32;
#pragma unroll
    for (int rf = 0; rf < 2; ++rf)
#pragma unroll
        for (int nf = 0; nf < 4; ++nf)
#pragma unroll
            for (int q = 0; q < 4; ++q) {
                int r = base + rf * 16 + lg * 4 + q;
                out[(size_t)r * 64 + nf * 16 + l15] = acc[rf][nf][q];
            }
}

// ================= gmax: A -> bnlrelu into ost -> C via direct ost fragment reads, max only =================
__global__ __launch_bounds__(256) void gmax3_kernel(const ushort* __restrict__ feat16,
                                                    const ushort* __restrict__ wt64,
                                                    const float* __restrict__ MW3,
                                                    const int* __restrict__ clusters,
                                                    const double* __restrict__ stats,
                                                    const float* __restrict__ lw_g, const float* __restrict__ lw_b,
                                                    unsigned* __restrict__ gmax, int n, int nb) {
    __shared__ float sb[128];
    __shared__ uint4 As[128 * 8];
    __shared__ ushort ost[128 * OSTR];
    __shared__ float sp[256];
    int l = blockIdx.x / nb, b = blockIdx.x % nb;
    int rb = b * 128;
    bn_sb(stats + (size_t)(2 * l) * 128, lw_g + l * 64, lw_b + l * 64, n, sb);
    int t = threadIdx.x, lane = t & 63, w = t >> 6;
    int arow = t >> 1, ah = t & 1;
    const int l15 = lane & 15, lg = lane >> 4;
    int rowA0 = w * 32 + l15, rowA1 = rowA0 + 16;
    const int* clus = clusters + (size_t)l * n;

    stage_a_bf16(feat16, As, rb + arow, n, arow, ah);
    __syncthreads();
    f4v accA[2][4];
#pragma unroll
    for (int rf = 0; rf < 2; ++rf)
#pragma unroll
        for (int nf = 0; nf < 4; ++nf)
#pragma unroll
            for (int q = 0; q < 4; ++q) accA[rf][nf][q] = 0.f;
    mfma_tileG(As, wt64 + (size_t)l * 4096, 64, 0, rowA0, rowA1, rowA0 & 7, rowA1 & 7, l15, lg, accA);
    tile_to_ost_bn(accA, ost, sb, w, lane);
    __syncthreads();
    f4v accC[2][4];
#pragma unroll
    for (int rf = 0; rf < 2; ++rf)
#pragma unroll
        for (int nf = 0; nf < 4; ++nf)
#pragma unroll
            for (int q = 0; q < 4; ++q) accC[rf][nf][q] = 0.f;
    mfma_tileOst(ost, wt64 + (size_t)(3 + l) * 4096, rowA0, rowA1, l15, lg, accC);
    float mx = -INFINITY;
#pragma unroll
    for (int rf = 0; rf < 2; ++rf)
#pragma unroll
        for (int q = 0; q < 4; ++q) {
            int r = rb + w * 32 + rf * 16 + lg * 4 + q;
            if (r < n) {
                int cc = clus[r];
                const float* mwr = MW3 + ((size_t)l * KCL + cc) * 64;
#pragma unroll
                for (int nf = 0; nf < 4; ++nf) {
                    int col = nf * 16 + l15;
                    mx = fmaxf(mx, accC[rf][nf][q] - mwr[col]);
                }
            }
        }
    sp[t] = mx;
    __syncthreads();
    for (int s = 128; s > 0; s >>= 1) {
        if (t < s) sp[t] = fmaxf(sp[t], sp[t + s]);
        __syncthreads();
    }
    if (t == 0) atomicMax(&gmax[l], encf(sp[0]));
}

// ================= seg3: block = (level, cluster); recompute C and E; ost direct reads =================
__global__ __launch_bounds__(256) void seg3_fused(const ushort* __restrict__ feat16,
                                                  const ushort* __restrict__ wt64,
                                                  const float* __restrict__ MW3,
                                                  const double* __restrict__ stats,
                                                  const float* __restrict__ lw_g, const float* __restrict__ lw_b,
                                                  const float* __restrict__ proj_g, const float* __restrict__ proj_b,
                                                  int n, const unsigned* __restrict__ gmax,
                                                  const int* __restrict__ cnts, const int* __restrict__ offs,
                                                  const int* __restrict__ perm, float* __restrict__ seg3) {
    int l = blockIdx.x >> 11, c = blockIdx.x & (KCL - 1);
    __shared__ float sbA[128], sbE[128];
    __shared__ uint4 As[128 * 8];
    __shared__ ushort ost[128 * OSTR];
    __shared__ float redd[256], redn[256];
    bn_sb(stats + (size_t)(2 * l) * 128, lw_g + l * 64, lw_b + l * 64, n, sbA);
    bn_sb(stats + (size_t)(2 * l + 1) * 128, proj_g + l * 64, proj_b + l * 64, n, sbE);
    int t = threadIdx.x, lane = t & 63, w = t >> 6;
    int arow = t >> 1, ah = t & 1;
    const int l15 = lane & 15, lg = lane >> 4;
    int rowA0 = w * 32 + l15, rowA1 = rowA0 + 16;
    float gm = decf(gmax[l]);
    int o = offs[l * KCL + c], m = cnts[l * KCL + c];
    const ushort* WmL = wt64 + (size_t)l * 4096;
    const ushort* WmW = wt64 + (size_t)(3 + l) * 4096;
    const ushort* WmP = wt64 + (size_t)(6 + l) * 4096;
    float mwv[4];
#pragma unroll
    for (int nf = 0; nf < 4; ++nf)
        mwv[nf] = MW3[((size_t)l * KCL + c) * 64 + nf * 16 + l15];
    float accd[4] = {0.f, 0.f, 0.f, 0.f}, accn[4] = {0.f, 0.f, 0.f, 0.f};

    for (int ch = 0; ch < m; ch += 128) {
        int j = ch + arow;
        int gi = (j < m) ? perm[o + j] : -1;
        __syncthreads();   // prior-iter ost reads / As reads done before restage
        stage_a_gather(feat16, As, gi, arow, ah);
        __syncthreads();
        f4v accA[2][4], accE[2][4];
#pragma unroll
        for (int rf = 0; rf < 2; ++rf)
#pragma unroll
            for (int nf = 0; nf < 4; ++nf)
#pragma unroll
                for (int q = 0; q < 4; ++q) { accA[rf][nf][q] = 0.f; accE[rf][nf][q] = 0.f; }
        mfma_tileG(As, WmL, 64, 0, rowA0, rowA1, rowA0 & 7, rowA1 & 7, l15, lg, accA);
        mfma_tileG(As, WmP, 64, 0, rowA0, rowA1, rowA0 & 7, rowA1 & 7, l15, lg, accE);
        tile_to_ost_bn(accA, ost, sbA, w, lane);
        __syncthreads();
        f4v accC[2][4];
#pragma unroll
        for (int rf = 0; rf < 2; ++rf)
#pragma unroll
            for (int nf = 0; nf < 4; ++nf)
#pragma unroll
                for (int q = 0; q < 4; ++q) accC[rf][nf][q] = 0.f;
        mfma_tileOst(ost, WmW, rowA0, rowA1, l15, lg, accC);
#pragma unroll
        for (int rf = 0; rf < 2; ++rf)
#pragma unroll
            for (int q = 0; q < 4; ++q) {
                int jr = ch + w * 32 + rf * 16 + lg * 4 + q;
                if (jr < m)
#pragma unroll
                    for (int nf = 0; nf < 4; ++nf) {
                        int col = nf * 16 + l15;
                        float d = expf(accC[rf][nf][q] - mwv[nf] - gm);
                        float pf = lrelu(accE[rf][nf][q] * sbE[col] + sbE[64 + col]);
                        accd[nf] += d;
                        accn[nf] += pf * d;
                    }
            }
    }
#pragma unroll
    for (int nf = 0; nf < 4; ++nf) {
        float s = accd[nf], s2 = accn[nf];
        s += __shfl_xor(s, 16); s += __shfl_xor(s, 32);
        s2 += __shfl_xor(s2, 16); s2 += __shfl_xor(s2, 32);
        if (lg == 0) {
            redd[w * 64 + nf * 16 + l15] = s;
            redn[w * 64 + nf * 16 + l15] = s2;
        }
    }
    __syncthreads();
    if (t < 64) {
        float sd = redd[t] + redd[64 + t] + redd[128 + t] + redd[192 + t];
        float sn = redn[t] + redn[64 + t] + redn[128 + t] + redn[192 + t];
        seg3[((size_t)l * KCL + c) * 64 + t] = sn / (sd + 1e-6f);
    }
}

// ================= fuse GEMM: P3 recomputed -> ost; phase0 via ost reads; t3 out + stats =================
__global__ __launch_bounds__(256) void fuse_mfma(const ushort* __restrict__ feat16,
                                                 const ushort* __restrict__ wt64,
                                                 const double* __restrict__ statsP,
                                                 const float* __restrict__ gg, const float* __restrict__ bb, int n,
                                                 const float* __restrict__ adp, const int* __restrict__ clusters,
                                                 const float* __restrict__ s3_0, const float* __restrict__ s3_1,
                                                 const float* __restrict__ s3_2, const ushort* __restrict__ WfT,
                                                 ushort* __restrict__ out, double* __restrict__ stats_out) {
    __shared__ uint4 As[128 * 8];
    __shared__ ushort ost[128 * OSTR];
    __shared__ float sb[128];
    int t = threadIdx.x, lane = t & 63, w = t >> 6;
    int rb = blockIdx.x * 128;
    int arow = t >> 1, ah = t & 1;
    const int l15 = lane & 15, lg = lane >> 4;
    int rowA0 = w * 32 + l15, rowA1 = rowA0 + 16;
    int row = rb + arow;

    bn_sb(statsP, gg, bb, n, sb);
    stage_a_bf16(feat16, As, row, n, arow, ah);
    __syncthreads();

    // P3 tile on the fly -> bnlrelu into ost
    f4v accP[2][4];
#pragma unroll
    for (int rf = 0; rf < 2; ++rf)
#pragma unroll
        for (int nf = 0; nf < 4; ++nf)
#pragma unroll
            for (int q = 0; q < 4; ++q) accP[rf][nf][q] = 0.f;
    mfma_tileG(As, wt64 + (size_t)9 * 4096, 64, 0, rowA0, rowA1, rowA0 & 7, rowA1 & 7, l15, lg, accP);
    tile_to_ost_bn(accP, ost, sb, w, lane);
    __syncthreads();   // ost visible; all As reads (P3 MFMA) complete -> safe to restage As

    // restage As with blend
    {
        float bv[32];
        if (row < n) {
            float a0 = adp[(size_t)row * 3 + 0], a1 = adp[(size_t)row * 3 + 1], a2 = adp[(size_t)row * 3 + 2];
            const float* r0 = s3_0 + (size_t)clusters[row] * 64 + ah * 32;
            const float* r1 = s3_1 + (size_t)clusters[(size_t)n + row] * 64 + ah * 32;
            const float* r2 = s3_2 + (size_t)clusters[2 * (size_t)n + row] * 64 + ah * 32;
#pragma unroll
            for (int i = 0; i < 32; ++i) bv[i] = a0 * r0[i] + a1 * r1[i] + a2 * r2[i];
        } else {
#pragma unroll
            for (int i = 0; i < 32; ++i) bv[i] = 0.f;
        }
        stage_a_vals(bv, As, arow, ah);
    }

    f4v acc[2][4];
#pragma unroll
    for (int rf = 0; rf < 2; ++rf)
#pragma unroll
        for (int nf = 0; nf < 4; ++nf)
#pragma unroll
            for (int q = 0; q < 4; ++q) acc[rf][nf][q] = 0.f;
    // phase 0: bnlrelu(P3) @ Wf[0:64]  (direct ost fragment reads, stride-64 rows not needed: ws=128)
    {
#pragma unroll
        for (int kb = 0; kb < 2; ++kb) {
            int gch = kb * 4 + lg;
            s8v a0 = *(const s8v*)(ost + rowA0 * OSTR + gch * 8);
            s8v a1 = *(const s8v*)(ost + rowA1 * OSTR + gch * 8);
#pragma unroll
            for (int nf = 0; nf < 4; ++nf) {
                int col = nf * 16 + l15;
                s8v bf = *(const s8v*)(WfT + (size_t)col * 128 + gch * 8);
                acc[0][nf] = __builtin_amdgcn_mfma_f32_16x16x32_bf16(a0, bf, acc[0][nf], 0, 0, 0);
                acc[1][nf] = __builtin_amdgcn_mfma_f32_16x16x32_bf16(a1, bf, acc[1][nf], 0, 0, 0);
            }
        }
    }
    __syncthreads();   // blend staged by all threads; ost reads complete
    // phase 1: blend @ Wf[64:128]
    mfma_tileG(As, WfT, 128, 64, rowA0, rowA1, rowA0 & 7, rowA1 & 7, l15, lg, acc);
    __syncthreads();   // all LDS reads done; reuse ost + As for epilogue
    float* red = (float*)As;
    tile_to_ost(acc, ost, w, lane);
    tile_stats(acc, red, stats_out, n, rb, w, lane, t);
    __syncthreads();
    ost_store(ost, out, n, rb, arow, ah);
    tile_stats_final(red, stats_out, t);
}

// ================= submanifold conv: A+W LDS double-buffered + zero-skip, coalesced out =================
__global__ __launch_bounds__(256) void subm_conv_db(const ushort* __restrict__ fin, const int* __restrict__ nbr,
                                                    const ushort* __restrict__ Wt, ushort* __restrict__ vout,
                                                    int n, double* __restrict__ stats_out) {
    __shared__ uint4 As[2][128 * 8];
    __shared__ uint4 Ws[2][64 * 8];
    int t = threadIdx.x;
    int lane = t & 63, w = t >> 6;
    int rb = blockIdx.x * 128;
    int arow = t >> 1, ah = t & 1;
    int wrow = t >> 2, wq = t & 3;
    const int l15 = lane & 15, lg = lane >> 4;
    int rowA0 = w * 32 + l15, rowA1 = rowA0 + 16;
    int swA0 = rowA0 & 7, swA1 = rowA1 & 7;
    const bool rowok = (rb + arow) < n;
    const int swa = arow & 7, sww = wrow & 7;

    f4v acc[2][4];
#pragma unroll
    for (int rf = 0; rf < 2; ++rf)
#pragma unroll
        for (int nf = 0; nf < 4; ++nf)
#pragma unroll
            for (int q = 0; q < 4; ++q) acc[rf][nf][q] = 0.f;

    bool fc0, fc1, wzc, wzn = false;
    {
        int gi = rowok ? nbr[rb + arow] : -1;
        uint4 v0 = {0, 0, 0, 0}, v1 = v0, v2 = v0, v3 = v0;
        if (gi >= 0) {
            const uint4* src = (const uint4*)(fin + (size_t)gi * 64) + ah * 4;
            v0 = src[0]; v1 = src[1]; v2 = src[2]; v3 = src[3];
        }
        unsigned long long bal = __ballot(gi >= 0);
        fc0 = (bal & 0xffffffffull) != 0ull;
        fc1 = (bal >> 32) != 0ull;
        wzc = (gi < 0);
        uint4* dst = As[0] + arow * 8;
        dst[(ah * 4 + 0) ^ swa] = v0;
        dst[(ah * 4 + 1) ^ swa] = v1;
        dst[(ah * 4 + 2) ^ swa] = v2;
        dst[(ah * 4 + 3) ^ swa] = v3;
        const uint4* ws = (const uint4*)(Wt + (size_t)wrow * 64);
        uint4* wdst = Ws[0] + wrow * 8;
        wdst[wq ^ sww] = ws[wq];
        wdst[(wq + 4) ^ sww] = ws[wq + 4];
    }
    int gi_next = rowok ? nbr[(size_t)n + rb + arow] : -1;
    int cur = 0;

    for (int k = 0; k < 27; ++k) {
        uint4 a0, a1, a2, a3, w0, w1;
        bool fn0 = false, fn1 = false, missn = true;
        if (k < 26) {
            missn = (gi_next < 0);
            a0 = a1 = a2 = a3 = (uint4){0, 0, 0, 0};
            if (!missn) {
                const uint4* src = (const uint4*)(fin + (size_t)gi_next * 64) + ah * 4;
                a0 = src[0]; a1 = src[1]; a2 = src[2]; a3 = src[3];
            }
            unsigned long long bal = __ballot(!missn);
            fn0 = (bal & 0xffffffffull) != 0ull;
            fn1 = (bal >> 32) != 0ull;
            const uint4* ws = (const uint4*)(Wt + (size_t)(k + 1) * 4096 + (size_t)wrow * 64);
            w0 = ws[wq];
            w1 = ws[wq + 4];
            if (k < 25) gi_next = rowok ? nbr[(size_t)(k + 2) * n + rb + arow] : -1;
        }
        __syncthreads();
        if (fc0 | fc1) {
            const s8v* Av = (const s8v*)As[cur];
            const s8v* Wv = (const s8v*)Ws[cur];
#pragma unroll
            for (int kb = 0; kb < 2; ++kb) {
                int gch = kb * 4 + lg;
                s8v bfr[4];
#pragma unroll
                for (int nf = 0; nf < 4; ++nf) {
                    int col = nf * 16 + l15;
                    bfr[nf] = Wv[col * 8 + (gch ^ (col & 7))];
                }
                if (fc0) {
                    s8v av0 = Av[rowA0 * 8 + (gch ^ swA0)];
#pragma unroll
                    for (int nf = 0; nf < 4; ++nf)
                        acc[0][nf] = __builtin_amdgcn_mfma_f32_16x16x32_bf16(av0, bfr[nf], acc[0][nf], 0, 0, 0);
                }
                if (fc1) {
                    s8v av1 = Av[rowA1 * 8 + (gch ^ swA1)];
#pragma unroll
                    for (int nf = 0; nf < 4; ++nf)
                        acc[1][nf] = __builtin_amdgcn_mfma_f32_16x16x32_bf16(av1, bfr[nf], acc[1][nf], 0, 0, 0);
                }
            }
        }
        if (k < 26) {
            if (!(missn && wzn)) {
                uint4* dst = As[cur ^ 1] + arow * 8;
                dst[(ah * 4 + 0) ^ swa] = a0;
                dst[(ah * 4 + 1) ^ swa] = a1;
                dst[(ah * 4 + 2) ^ swa] = a2;
                dst[(ah * 4 + 3) ^ swa] = a3;
            }
            uint4* wdst = Ws[cur ^ 1] + wrow * 8;
            wdst[wq ^ sww] = w0;
            wdst[(wq + 4) ^ sww] = w1;
            cur ^= 1;
            bool nw = wzc;
            wzc = missn;
            wzn = nw;
            fc0 = fn0;
            fc1 = fn1;
        }
    }
    __syncthreads();
    ushort* ost = (ushort*)As[0];
    float* red = (float*)Ws[0];
    tile_to_ost(acc, ost, w, lane);
    tile_stats(acc, red, stats_out, n, rb, w, lane, t);
    __syncthreads();
    ost_store(ost, vout, n, rb, arow, ah);
    tile_stats_final(red, stats_out, t);
}

// ---------------- f16 = bf16(lrelu(bn(t3)) + feat) ----------------
__global__ __launch_bounds__(256) void addfeat_kernel(const ushort* __restrict__ t3, const double* __restrict__ stats,
                                                      const float* __restrict__ g, const float* __restrict__ b,
                                                      const float* __restrict__ feat, ushort* __restrict__ f16,
                                                      int n) {
    __shared__ float sb[128];
    bn_sb(stats, g, b, n, sb);
    long total4 = (long)n * 16;
    for (long i = (long)blockIdx.x * 256 + threadIdx.x; i < total4; i += (long)gridDim.x * 256) {
        int c0 = (int)(i & 15) * 4;
        ushort4 xv = ((const ushort4*)t3)[i];
        float4 fz = ((const float4*)feat)[i];
        ushort4 u;
        u.x = f2bf(lrelu(bf2f(xv.x) * sb[c0 + 0] + sb[64 + c0 + 0]) + fz.x);
        u.y = f2bf(lrelu(bf2f(xv.y) * sb[c0 + 1] + sb[64 + c0 + 1]) + fz.y);
        u.z = f2bf(lrelu(bf2f(xv.z) * sb[c0 + 2] + sb[64 + c0 + 2]) + fz.z);
        u.w = f2bf(lrelu(bf2f(xv.w) * sb[c0 + 3] + sb[64 + c0 + 3]) + fz.w);
        ((ushort4*)f16)[i] = u;
    }
}

// ---------------- o16 = bf16(lrelu(bn(v16))) ----------------
__global__ __launch_bounds__(256) void bnlrelu_tobf16_kernel(const ushort* __restrict__ v,
                                                             const double* __restrict__ stats,
                                                             const float* __restrict__ g, const float* __restrict__ b,
                                                             ushort* __restrict__ o16, int n) {
    __shared__ float sb[128];
    bn_sb(stats, g, b, n, sb);
    long total4 = (long)n * 16;
    for (long i = (long)blockIdx.x * 256 + threadIdx.x; i < total4; i += (long)gridDim.x * 256) {
        int c0 = (int)(i & 15) * 4;
        ushort4 xv = ((const ushort4*)v)[i];
        ushort4 u;
        u.x = f2bf(lrelu(bf2f(xv.x) * sb[c0 + 0] + sb[64 + c0 + 0]));
        u.y = f2bf(lrelu(bf2f(xv.y) * sb[c0 + 1] + sb[64 + c0 + 1]));
        u.z = f2bf(lrelu(bf2f(xv.z) * sb[c0 + 2] + sb[64 + c0 + 2]));
        u.w = f2bf(lrelu(bf2f(xv.w) * sb[c0 + 3] + sb[64 + c0 + 3]));
        ((ushort4*)o16)[i] = u;
    }
}

// ---------------- out = lrelu(bn(w16) + f16) ----------------
__global__ __launch_bounds__(256) void final_kernel(const ushort* __restrict__ w16, const double* __restrict__ stats,
                                                    const float* __restrict__ g, const float* __restrict__ b,
                                                    const ushort* __restrict__ f16, float* __restrict__ out, int n) {
    __shared__ float sb[128];
    bn_sb(stats, g, b, n, sb);
    long total4 = (long)n * 16;
    for (long i = (long)blockIdx.x * 256 + threadIdx.x; i < total4; i += (long)gridDim.x * 256) {
        int c0 = (int)(i & 15) * 4;
        ushort4 xv = ((const ushort4*)w16)[i];
        ushort4 u = ((const ushort4*)f16)[i];
        float4 y;
        y.x = lrelu(bf2f(xv.x) * sb[c0 + 0] + sb[64 + c0 + 0] + bf2f(u.x));
        y.y = lrelu(bf2f(xv.y) * sb[c0 + 1] + sb[64 + c0 + 1] + bf2f(u.y));
        y.z = lrelu(bf2f(xv.z) * sb[c0 + 2] + sb[64 + c0 + 2] + bf2f(u.z));
        y.w = lrelu(bf2f(xv.w) * sb[c0 + 3] + sb[64 + c0 + 3] + bf2f(u.w));
        ((float4*)out)[i] = y;
    }
}

extern "C" void kernel_launch(void* const* d_in, const int* in_sizes, int n_in,
                              void* d_out, int out_size, void* d_ws, size_t ws_size,
                              hipStream_t stream) {
    const float* feat = (const float*)d_in[0];
    const float* lw_W = (const float*)d_in[1];
    const float* lw_g = (const float*)d_in[2];
    const float* lw_b = (const float*)d_in[3];
    const float* w_W = (const float*)d_in[4];
    const float* proj_W = (const float*)d_in[5];
    const float* proj_g = (const float*)d_in[6];
    const float* proj_b = (const float*)d_in[7];
    const float* adaptive_W = (const float*)d_in[8];
    const float* fuse_W = (const float*)d_in[9];
    const float* fuse_g = (const float*)d_in[10];
    const float* fuse_b = (const float*)d_in[11];
    const float* conv1_W = (const float*)d_in[12];
    const float* bn1_g = (const float*)d_in[13];
    const float* bn1_b = (const float*)d_in[14];
    const float* conv2_W = (const float*)d_in[15];
    const float* bn2_g = (const float*)d_in[16];
    const float* bn2_b = (const float*)d_in[17];
    const int* clusters = (const int*)d_in[18];
    const int* nbr = (const int*)d_in[19];

    const int n = in_sizes[0] / 64;

    char* ws = (char*)d_ws;
    size_t off = 0;
    auto alloc = [&](size_t bytes) -> size_t {
        size_t o = off;
        off = (off + bytes + 255) & ~(size_t)255;
        return o;
    };
    // zeroed region
    size_t cnt_off = alloc((size_t)3 * KCL * 4);
    size_t stats_off = alloc((size_t)10 * 128 * 8);
    size_t gmax_off = alloc(16);
    size_t zbytes = off;
    // non-zeroed
    size_t offs_off = alloc((size_t)3 * KCL * 4);
    size_t cur_off = alloc((size_t)3 * KCL * 4);
    size_t perm_off = alloc((size_t)3 * n * 4);
    size_t mean_off = alloc((size_t)3 * KCL * 64 * 4);
    size_t mw_off = alloc((size_t)3 * KCL * 64 * 4);
    size_t seg3_off = alloc((size_t)3 * KCL * 64 * 4);
    size_t adp_off = alloc((size_t)n * 3 * 4);
    size_t feat16_off = alloc((size_t)n * 64 * 2);
    size_t ra_off = alloc((size_t)3 * n * 64 * 2);   // t3buf, fbuf16, c1out
    size_t re_off = alloc((size_t)2 * n * 64 * 2);   // cbuf, c2out
    size_t wt64_off = alloc((size_t)64 * 4096 * 2);
    size_t wfT_off = alloc((size_t)8192 * 2);

    int* cnts = (int*)(ws + cnt_off);
    double* stats = (double*)(ws + stats_off);
    unsigned* gmax = (unsigned*)(ws + gmax_off);
    int* offs = (int*)(ws + offs_off);
    int* cursor = (int*)(ws + cur_off);
    int* perm = (int*)(ws + perm_off);
    float* meanB3 = (float*)(ws + mean_off);
    float* MW3 = (float*)(ws + mw_off);
    float* seg3 = (float*)(ws + seg3_off);
    float* adp = (float*)(ws + adp_off);
    ushort* feat16 = (ushort*)(ws + feat16_off);
    ushort* RA = (ushort*)(ws + ra_off);
    ushort* RE = (ushort*)(ws + re_off);
    ushort* wt64 = (ushort*)(ws + wt64_off);
    ushort* wfT = (ushort*)(ws + wfT_off);
    float* outp = (float*)d_out;

    ushort* t3buf = RA;
    ushort* fbuf16 = RA + (size_t)n * 64;
    ushort* c1out = RA + (size_t)2 * n * 64;
    ushort* cbuf = RE;
    ushort* c2out = RE + (size_t)n * 64;

    const ushort* wW16 = wt64 + (size_t)3 * 4096;
    const ushort* conv1W16 = wt64 + (size_t)10 * 4096;
    const ushort* conv2W16 = wt64 + (size_t)37 * 4096;

    hipMemsetAsync(d_ws, 0, zbytes, stream);

    const int GEMM_BLK = (n + 127) / 128;
    const int EW_BLK = 2048;

    prep_wt64<<<64, 256, 0, stream>>>(lw_W, w_W, proj_W, conv1_W, conv2_W, wt64);
    prep_fuse<<<1, 256, 0, stream>>>(fuse_W, wfT);
    adp_cvt_kernel<<<1024, 256, 0, stream>>>(feat, adaptive_W, adp, feat16, n);

    hist3_kernel<<<384, 256, 0, stream>>>(clusters, cnts, n);
    scan_kernel<<<3, 256, 0, stream>>>(cnts, offs, cursor, n);
    scatter_kernel<<<1024, 256, 0, stream>>>(clusters, cursor, perm, n);

    // BN stats for all 7 linear products (no intermediate materialization)
    stats7_gemm<<<GEMM_BLK, 256, 0, stream>>>(feat16, wt64, n, stats);
    // meanB_l[c] = mean over cluster of bnlrelu(feat @ lw_l)
    mean3_fused<<<3 * KCL, 256, 0, stream>>>(feat16, wt64, stats, lw_g, lw_b, n, cnts, offs, perm,
                                             meanB3);
    // MW_l = meanB_l @ wW_l
    mw3_gemm<<<3 * 16, 256, 0, stream>>>(meanB3, wW16, MW3);
    // gmax_l = max over C_l (recomputed, not stored)
    gmax3_kernel<<<3 * GEMM_BLK, 256, 0, stream>>>(feat16, wt64, MW3, clusters, stats, lw_g, lw_b,
                                                   gmax, n, GEMM_BLK);
    // seg3_l[c] = softmax-pool, recomputing C and E on the fly
    seg3_fused<<<3 * KCL, 256, 0, stream>>>(feat16, wt64, MW3, stats, lw_g, lw_b, proj_g, proj_b,
                                            n, gmax, cnts, offs, perm, seg3);

    // t3 = [bnlrelu(feat@proj3) | blend] @ fuse_W + stats(7)
    fuse_mfma<<<GEMM_BLK, 256, 0, stream>>>(feat16, wt64, stats + 6 * 128, proj_g + 192, proj_b + 192,
                                            n, adp, clusters,
                                            seg3, seg3 + (size_t)KCL * 64, seg3 + (size_t)2 * KCL * 64,
                                            wfT, t3buf, stats + 7 * 128);
    // f = lrelu(bn(t3)) + feat  (bf16)
    addfeat_kernel<<<EW_BLK, 256, 0, stream>>>(t3buf, stats + 7 * 128, fuse_g, fuse_b, feat, fbuf16, n);

    // conv1 -> c1out (+stats 8); bn1+lrelu -> cbuf
    subm_conv_db<<<GEMM_BLK, 256, 0, stream>>>(fbuf16, nbr, conv1W16, c1out, n, stats + 8 * 128);
    bnlrelu_tobf16_kernel<<<EW_BLK, 256, 0, stream>>>(c1out, stats + 8 * 128, bn1_g, bn1_b, cbuf, n);

    // conv2 -> c2out (+stats 9); out = lrelu(bn2 + f)
    subm_conv_db<<<GEMM_BLK, 256, 0, stream>>>(cbuf, nbr, conv2W16, c2out, n, stats + 9 * 128);
    final_kernel<<<EW_BLK, 256, 0, stream>>>(c2out, stats + 9 * 128, bn2_g, bn2_b, fbuf16, outp, n);
}

// Round 14
// 589.197 us; speedup vs baseline: 1.0312x; 1.0312x over previous
//
#include <hip/hip_runtime.h>
#include <hip/hip_bf16.h>
#include <math.h>

#define KCL 2048
#define LRELU_NEG 0.01f
#define EPSBN 1e-5f

using s8v = __attribute__((ext_vector_type(8))) short;   // 8 bf16 (4 VGPRs)
using f4v = __attribute__((ext_vector_type(4))) float;   // MFMA accumulator

union U8 { ushort u[8]; uint4 v; };

__device__ __forceinline__ float lrelu(float x) { return x > 0.f ? x : LRELU_NEG * x; }
__device__ __forceinline__ ushort f2bf(float f) {
    __hip_bfloat16 h = __float2bfloat16(f);
    return *reinterpret_cast<ushort*>(&h);
}
__device__ __forceinline__ float bf2f(ushort u) { return __uint_as_float(((unsigned)u) << 16); }

__device__ __forceinline__ unsigned encf(float f) {
    unsigned u = __float_as_uint(f);
    return (u & 0x80000000u) ? ~u : (u | 0x80000000u);
}
__device__ __forceinline__ float decf(unsigned u) {
    return __uint_as_float((u & 0x80000000u) ? (u & 0x7fffffffu) : ~u);
}

// finalize BN stats into LDS scale/bias: y = x*sb[col] + sb[64+col]
__device__ __forceinline__ void bn_sb(const double* __restrict__ stats, const float* __restrict__ g,
                                      const float* __restrict__ b, int n, float* sb) {
    int t = threadIdx.x;
    if (t < 64) {
        float mean = (float)(stats[t] / n);
        float ex2 = (float)(stats[64 + t] / n);
        float var = fmaxf(ex2 - mean * mean, 0.f);
        float rstd = rsqrtf(var + EPSBN);
        float sc = rstd * g[t];
        sb[t] = sc;
        sb[64 + t] = b[t] - mean * sc;
    }
    __syncthreads();
}

// MFMA over a staged A tile with B fragments loaded straight from global (L1/L2-hot).
__device__ __forceinline__ void mfma_tileG(const uint4* As, const ushort* Wmat, int ws, int koff,
                                           int rowA0, int rowA1, int swA0, int swA1,
                                           int l15, int lg, f4v acc[2][4]) {
    const s8v* Av = (const s8v*)As;
#pragma unroll
    for (int kb = 0; kb < 2; ++kb) {
        int gch = kb * 4 + lg;
        s8v a0 = Av[rowA0 * 8 + (gch ^ swA0)];
        s8v a1 = Av[rowA1 * 8 + (gch ^ swA1)];
#pragma unroll
        for (int nf = 0; nf < 4; ++nf) {
            int col = nf * 16 + l15;
            s8v bf = *(const s8v*)(Wmat + (size_t)col * ws + koff + gch * 8);
            acc[0][nf] = __builtin_amdgcn_mfma_f32_16x16x32_bf16(a0, bf, acc[0][nf], 0, 0, 0);
            acc[1][nf] = __builtin_amdgcn_mfma_f32_16x16x32_bf16(a1, bf, acc[1][nf], 0, 0, 0);
        }
    }
}

__device__ __forceinline__ void stage_a_bf16(const ushort* S, uint4* As, int row, int n, int arow, int ah) {
    uint4 c0 = {0, 0, 0, 0}, c1 = c0, c2 = c0, c3 = c0;
    if (row < n) {
        const uint4* s = (const uint4*)(S + (size_t)row * 64) + ah * 4;
        c0 = s[0]; c1 = s[1]; c2 = s[2]; c3 = s[3];
    }
    int sw = arow & 7;
    uint4* dst = As + arow * 8;
    dst[(ah * 4 + 0) ^ sw] = c0;
    dst[(ah * 4 + 1) ^ sw] = c1;
    dst[(ah * 4 + 2) ^ sw] = c2;
    dst[(ah * 4 + 3) ^ sw] = c3;
}

// gather-stage by explicit index (gi < 0 -> zero row)
__device__ __forceinline__ void stage_a_gather(const ushort* S, uint4* As, int gi, int arow, int ah) {
    uint4 c0 = {0, 0, 0, 0}, c1 = c0, c2 = c0, c3 = c0;
    if (gi >= 0) {
        const uint4* s = (const uint4*)(S + (size_t)gi * 64) + ah * 4;
        c0 = s[0]; c1 = s[1]; c2 = s[2]; c3 = s[3];
    }
    int sw = arow & 7;
    uint4* dst = As + arow * 8;
    dst[(ah * 4 + 0) ^ sw] = c0;
    dst[(ah * 4 + 1) ^ sw] = c1;
    dst[(ah * 4 + 2) ^ sw] = c2;
    dst[(ah * 4 + 3) ^ sw] = c3;
}

__device__ __forceinline__ void stage_a_vals(const float* vals, uint4* As, int arow, int ah) {
    int sw = arow & 7;
    uint4* dst = As + arow * 8;
#pragma unroll
    for (int c = 0; c < 4; ++c) {
        U8 u;
#pragma unroll
        for (int e = 0; e < 8; ++e) u.u[e] = f2bf(vals[c * 8 + e]);
        dst[(ah * 4 + c) ^ sw] = u.v;
    }
}

// ---------------- weight prep: 64 matrices of 64x64, transposed -> bf16 ----------------
__global__ __launch_bounds__(256) void prep_wt64(const float* __restrict__ lw, const float* __restrict__ wW,
                                                 const float* __restrict__ proj, const float* __restrict__ c1,
                                                 const float* __restrict__ c2, ushort* __restrict__ wt) {
    int bk = blockIdx.x;
    const float* W;
    if (bk < 3) W = lw + (size_t)bk * 4096;
    else if (bk < 6) W = wW + (size_t)(bk - 3) * 4096;
    else if (bk < 10) W = proj + (size_t)(bk - 6) * 4096;
    else if (bk < 37) W = c1 + (size_t)(bk - 10) * 4096;
    else W = c2 + (size_t)(bk - 37) * 4096;
    ushort* o = wt + (size_t)bk * 4096;
    for (int i = threadIdx.x; i < 4096; i += 256) {
        int kk = i >> 6, cc = i & 63;
        o[cc * 64 + kk] = f2bf(W[i]);
    }
}

__global__ __launch_bounds__(256) void prep_fuse(const float* __restrict__ Wf, ushort* __restrict__ o) {
    for (int i = threadIdx.x; i < 8192; i += 256) {
        int kk = i >> 6, cc = i & 63;
        o[cc * 128 + kk] = f2bf(Wf[i]);
    }
}

// ---------------- adaptive weights + fp32->bf16 convert (one pass over feat) ----------------
__global__ __launch_bounds__(256) void adp_cvt_kernel(const float* __restrict__ feat, const float* __restrict__ aW,
                                                      float* __restrict__ adp, ushort* __restrict__ feat16, int n) {
    __shared__ float w[192];
    for (int i = threadIdx.x; i < 192; i += 256) w[i] = aW[i];
    __syncthreads();
    for (long row = (long)blockIdx.x * 256 + threadIdx.x; row < n; row += (long)gridDim.x * 256) {
        const float4* fr = (const float4*)(feat + row * 64);
        ushort4* fo = (ushort4*)(feat16 + row * 64);
        float l0 = 0.f, l1 = 0.f, l2 = 0.f;
#pragma unroll
        for (int q = 0; q < 16; ++q) {
            float4 x = fr[q];
            int k = q * 4;
            l0 += x.x * w[k * 3 + 0] + x.y * w[k * 3 + 3] + x.z * w[k * 3 + 6] + x.w * w[k * 3 + 9];
            l1 += x.x * w[k * 3 + 1] + x.y * w[k * 3 + 4] + x.z * w[k * 3 + 7] + x.w * w[k * 3 + 10];
            l2 += x.x * w[k * 3 + 2] + x.y * w[k * 3 + 5] + x.z * w[k * 3 + 8] + x.w * w[k * 3 + 11];
            ushort4 u;
            u.x = f2bf(x.x); u.y = f2bf(x.y); u.z = f2bf(x.z); u.w = f2bf(x.w);
            fo[q] = u;
        }
        float m = fmaxf(l0, fmaxf(l1, l2));
        float e0 = expf(l0 - m), e1 = expf(l1 - m), e2 = expf(l2 - m);
        float inv = 1.f / (e0 + e1 + e2);
        adp[row * 3 + 0] = e0 * inv;
        adp[row * 3 + 1] = e1 * inv;
        adp[row * 3 + 2] = e2 * inv;
    }
}

// ---------------- cluster histogram, all 3 levels ----------------
__global__ __launch_bounds__(256) void hist3_kernel(const int* __restrict__ clusters, int* __restrict__ cnt,
                                                    int n) {
    __shared__ int h[KCL];
    int l = blockIdx.x % 3;
    int nb = gridDim.x / 3, bi = blockIdx.x / 3;
    for (int i = threadIdx.x; i < KCL; i += 256) h[i] = 0;
    __syncthreads();
    const int* cl = clusters + (size_t)l * n;
    for (long i = (long)bi * 256 + threadIdx.x; i < n; i += (long)nb * 256)
        atomicAdd(&h[cl[i]], 1);
    __syncthreads();
    for (int i = threadIdx.x; i < KCL; i += 256) {
        int v = h[i];
        if (v) atomicAdd(&cnt[l * KCL + i], v);
    }
}

// ---------------- exclusive scan -> absolute offsets + cursor ----------------
__global__ __launch_bounds__(256) void scan_kernel(const int* __restrict__ cnt, int* __restrict__ off,
                                                   int* __restrict__ cursor, int n) {
    int l = blockIdx.x;
    const int* c = cnt + l * KCL;
    __shared__ int part[256];
    __shared__ int pref[256];
    int t = threadIdx.x;
    int base = t * 8;
    int v[8];
    int s = 0;
#pragma unroll
    for (int j = 0; j < 8; ++j) { v[j] = c[base + j]; s += v[j]; }
    part[t] = s;
    __syncthreads();
    if (t == 0) {
        int acc = 0;
        for (int i = 0; i < 256; ++i) { pref[i] = acc; acc += part[i]; }
    }
    __syncthreads();
    int acc = pref[t] + l * n;
#pragma unroll
    for (int j = 0; j < 8; ++j) {
        off[l * KCL + base + j] = acc;
        cursor[l * KCL + base + j] = acc;
        acc += v[j];
    }
}

// ---------------- scatter rows into cluster-sorted perm ----------------
__global__ __launch_bounds__(256) void scatter_kernel(const int* __restrict__ clusters, int* __restrict__ cursor,
                                                      int* __restrict__ perm, int n) {
    long n3 = (long)n * 3;
    for (long i = (long)blockIdx.x * 256 + threadIdx.x; i < n3; i += (long)gridDim.x * 256) {
        int l = (i >= n) + (i >= 2 * (long)n);
        int c = clusters[i];
        int pos = atomicAdd(&cursor[l * KCL + c], 1);
        perm[pos] = (int)(i - (long)l * n);
    }
}

// ---------------- one GEMM pass over a staged A tile: optional bf16 out + stats ----------------
template <int WR>
__device__ __forceinline__ void mega_one(const uint4* As, float* red, const ushort* Wmat, ushort* out,
                                         double* statp, int n, int rb, int w, int lane, int t) {
    const int l15 = lane & 15, lg = lane >> 4;
    int rowA0 = w * 32 + l15, rowA1 = rowA0 + 16;
    f4v acc[2][4];
#pragma unroll
    for (int rf = 0; rf < 2; ++rf)
#pragma unroll
        for (int nf = 0; nf < 4; ++nf)
#pragma unroll
            for (int q = 0; q < 4; ++q) acc[rf][nf][q] = 0.f;
    mfma_tileG(As, Wmat, 64, 0, rowA0, rowA1, rowA0 & 7, rowA1 & 7, l15, lg, acc);
    int base = rb + w * 32;
    if (WR) {
#pragma unroll
        for (int rf = 0; rf < 2; ++rf)
#pragma unroll
            for (int nf = 0; nf < 4; ++nf)
#pragma unroll
                for (int q = 0; q < 4; ++q) {
                    int r = base + rf * 16 + lg * 4 + q;
                    if (r < n) out[(size_t)r * 64 + nf * 16 + l15] = f2bf(acc[rf][nf][q]);
                }
    }
#pragma unroll
    for (int nf = 0; nf < 4; ++nf) {
        float s = 0.f, s2 = 0.f;
#pragma unroll
        for (int rf = 0; rf < 2; ++rf)
#pragma unroll
            for (int q = 0; q < 4; ++q) {
                int r = base + rf * 16 + lg * 4 + q;
                if (r < n) {
                    float v = acc[rf][nf][q];
                    s += v;
                    s2 += v * v;
                }
            }
        s += __shfl_xor(s, 16); s += __shfl_xor(s, 32);
        s2 += __shfl_xor(s2, 16); s2 += __shfl_xor(s2, 32);
        if (lg == 0) {
            red[w * 64 + nf * 16 + l15] = s;
            red[256 + w * 64 + nf * 16 + l15] = s2;
        }
    }
    __syncthreads();
    if (t < 64) {
        float s = red[t] + red[64 + t] + red[128 + t] + red[192 + t];
        float s2 = red[256 + t] + red[320 + t] + red[384 + t] + red[448 + t];
        atomicAdd(&statp[t], (double)s);
        atomicAdd(&statp[64 + t], (double)s2);
    }
    __syncthreads();
}

// ================= mega GEMM: stats for 7 products; write only A0-2 and P3 =================
__global__ __launch_bounds__(256) void mega7_gemm(const ushort* __restrict__ feat16,
                                                  const ushort* __restrict__ wt64,
                                                  ushort* __restrict__ o0, ushort* __restrict__ o1,
                                                  ushort* __restrict__ o2, ushort* __restrict__ o6,
                                                  int n, double* __restrict__ stats) {
    __shared__ uint4 As[128 * 8];
    __shared__ float red[512];
    int t = threadIdx.x, lane = t & 63, w = t >> 6;
    int rb = blockIdx.x * 128;
    int arow = t >> 1, ah = t & 1;
    stage_a_bf16(feat16, As, rb + arow, n, arow, ah);
    __syncthreads();
    // weights: lw0-2 at slots 0-2 (stats 0,2,4, WRITE); proj0-2 at 6-8 (stats 1,3,5, no write);
    // proj3 at slot 9 (stats 6, WRITE)
    mega_one<1>(As, red, wt64 + (size_t)0 * 4096, o0, stats + 0 * 128, n, rb, w, lane, t);
    mega_one<1>(As, red, wt64 + (size_t)1 * 4096, o1, stats + 2 * 128, n, rb, w, lane, t);
    mega_one<1>(As, red, wt64 + (size_t)2 * 4096, o2, stats + 4 * 128, n, rb, w, lane, t);
    mega_one<0>(As, red, wt64 + (size_t)6 * 4096, nullptr, stats + 1 * 128, n, rb, w, lane, t);
    mega_one<0>(As, red, wt64 + (size_t)7 * 4096, nullptr, stats + 3 * 128, n, rb, w, lane, t);
    mega_one<0>(As, red, wt64 + (size_t)8 * 4096, nullptr, stats + 5 * 128, n, rb, w, lane, t);
    mega_one<1>(As, red, wt64 + (size_t)9 * 4096, o6, stats + 6 * 128, n, rb, w, lane, t);
}

// ================= meanB for all 3 levels (block = (level, cluster)) =================
__global__ __launch_bounds__(256) void reduce_mean3_kernel(const ushort* __restrict__ A3,
                                                           const double* __restrict__ stats,
                                                           const float* __restrict__ lw_g,
                                                           const float* __restrict__ lw_b, int n,
                                                           const int* __restrict__ cnts, const int* __restrict__ offs,
                                                           const int* __restrict__ perm,
                                                           float* __restrict__ meanB3) {
    int l = blockIdx.x >> 11, c = blockIdx.x & (KCL - 1);
    const ushort* A = A3 + (size_t)l * n * 64;
    __shared__ float sb[128];
    bn_sb(stats + (size_t)(2 * l) * 128, lw_g + l * 64, lw_b + l * 64, n, sb);
    int t = threadIdx.x, col = t & 63, rg = t >> 6;
    int o = offs[l * KCL + c], m = cnts[l * KCL + c];
    float acc = 0.f;
    float sc = sb[col], bi = sb[64 + col];
    for (int j = rg; j < m; j += 4) {
        int row = perm[o + j];
        acc += lrelu(bf2f(A[(size_t)row * 64 + col]) * sc + bi);
    }
    __shared__ float red[256];
    red[t] = acc;
    __syncthreads();
    if (t < 64) {
        float s = red[t] + red[t + 64] + red[t + 128] + red[t + 192];
        float cf = (float)m;
        if (cf < 1.f) cf = 1.f;
        meanB3[(size_t)l * KCL * 64 + (size_t)c * 64 + col] = s / cf;
    }
}

// ================= MW for all 3 levels: meanB_l @ wW_l =================
__global__ __launch_bounds__(256) void mw3_gemm(const float* __restrict__ meanB3, const ushort* __restrict__ wW16,
                                                float* __restrict__ MW3) {
    __shared__ uint4 As[128 * 8];
    int l = blockIdx.x >> 4, b = blockIdx.x & 15;
    const float* src = meanB3 + (size_t)l * KCL * 64;
    float* out = MW3 + (size_t)l * KCL * 64;
    int t = threadIdx.x, lane = t & 63, w = t >> 6;
    int rb = b * 128;
    int arow = t >> 1, ah = t & 1;
    const int l15 = lane & 15, lg = lane >> 4;
    {
        float vals[32];
        const float4* s = (const float4*)(src + (size_t)(rb + arow) * 64 + ah * 32);
#pragma unroll
        for (int q = 0; q < 8; ++q) {
            float4 x = s[q];
            vals[q * 4 + 0] = x.x; vals[q * 4 + 1] = x.y;
            vals[q * 4 + 2] = x.z; vals[q * 4 + 3] = x.w;
        }
        stage_a_vals(vals, As, arow, ah);
    }
    __syncthreads();
    f4v acc[2][4];
#pragma unroll
    for (int rf = 0; rf < 2; ++rf)
#pragma unroll
        for (int nf = 0; nf < 4; ++nf)
#pragma unroll
            for (int q = 0; q < 4; ++q) acc[rf][nf][q] = 0.f;
    int rowA0 = w * 32 + l15, rowA1 = rowA0 + 16;
    mfma_tileG(As, wW16 + (size_t)l * 4096, 64, 0, rowA0, rowA1, rowA0 & 7, rowA1 & 7, l15, lg, acc);
    int base = rb + w * 32;
#pragma unroll
    for (int rf = 0; rf < 2; ++rf)
#pragma unroll
        for (int nf = 0; nf < 4; ++nf)
#pragma unroll
            for (int q = 0; q < 4; ++q) {
                int r = base + rf * 16 + lg * 4 + q;
                out[(size_t)r * 64 + nf * 16 + l15] = acc[rf][nf][q];
            }
}

// ================= C_l = bnlrelu(A_l) @ wW_l - MW_l[clus], IN PLACE over A, + gmax =================
__global__ __launch_bounds__(256) void cgemm3(ushort* __restrict__ A3io, const ushort* __restrict__ wW16,
                                              const float* __restrict__ MW3, const int* __restrict__ clusters,
                                              const double* __restrict__ stats, const float* __restrict__ lw_g,
                                              const float* __restrict__ lw_b,
                                              unsigned* __restrict__ gmax, int n, int nb) {
    __shared__ uint4 As[128 * 8];
    __shared__ float sb[128];
    int l = blockIdx.x / nb, b = blockIdx.x % nb;
    ushort* A = A3io + (size_t)l * n * 64;
    const float* MW = MW3 + (size_t)l * KCL * 64;
    const int* clus = clusters + (size_t)l * n;
    int t = threadIdx.x, lane = t & 63, w = t >> 6;
    int rb = b * 128;
    int arow = t >> 1, ah = t & 1;
    const int l15 = lane & 15, lg = lane >> 4;

    bn_sb(stats + (size_t)(2 * l) * 128, lw_g + l * 64, lw_b + l * 64, n, sb);
    {
        int row = rb + arow;
        float vals[32];
        if (row < n) {
            const U8* s8p = (const U8*)(A + (size_t)row * 64 + ah * 32);
#pragma unroll
            for (int c = 0; c < 4; ++c) {
                U8 u = s8p[c];
#pragma unroll
                for (int e = 0; e < 8; ++e) {
                    int col = ah * 32 + c * 8 + e;
                    vals[c * 8 + e] = lrelu(bf2f(u.u[e]) * sb[col] + sb[64 + col]);
                }
            }
        } else {
#pragma unroll
            for (int i = 0; i < 32; ++i) vals[i] = 0.f;
        }
        stage_a_vals(vals, As, arow, ah);
    }
    __syncthreads();
    f4v acc[2][4];
#pragma unroll
    for (int rf = 0; rf < 2; ++rf)
#pragma unroll
        for (int nf = 0; nf < 4; ++nf)
#pragma unroll
            for (int q = 0; q < 4; ++q) acc[rf][nf][q] = 0.f;
    int rowA0 = w * 32 + l15, rowA1 = rowA0 + 16;
    mfma_tileG(As, wW16 + (size_t)l * 4096, 64, 0, rowA0, rowA1, rowA0 & 7, rowA1 & 7, l15, lg, acc);
    int base = rb + w * 32;
    float m = -INFINITY;
#pragma unroll
    for (int rf = 0; rf < 2; ++rf)
#pragma unroll
        for (int q = 0; q < 4; ++q) {
            int r = base + rf * 16 + lg * 4 + q;
            if (r < n) {
                int c = clus[r];
                const float* mwr = MW + (size_t)c * 64;
#pragma unroll
                for (int nf = 0; nf < 4; ++nf) {
                    int col = nf * 16 + l15;
                    float v = acc[rf][nf][q] - mwr[col];
                    A[(size_t)r * 64 + col] = f2bf(v);   // in place: C over A
                    m = fmaxf(m, v);
                }
            }
        }
    __syncthreads();
    float* sp = (float*)As;
    sp[t] = m;
    __syncthreads();
    for (int s = 128; s > 0; s >>= 1) {
        if (t < s) sp[t] = fmaxf(sp[t], sp[t + s]);
        __syncthreads();
    }
    if (t == 0) atomicMax(&gmax[l], encf(sp[0]));
}

// ================= seg3: gather feat16 -> E via MFMA; C gathered from materialized C3 =================
__global__ __launch_bounds__(256) void seg3g_kernel(const ushort* __restrict__ C3,
                                                    const ushort* __restrict__ feat16,
                                                    const ushort* __restrict__ wt64,
                                                    const double* __restrict__ stats,
                                                    const float* __restrict__ proj_g,
                                                    const float* __restrict__ proj_b,
                                                    int n, const unsigned* __restrict__ gmax,
                                                    const int* __restrict__ cnts, const int* __restrict__ offs,
                                                    const int* __restrict__ perm, float* __restrict__ seg3) {
    int l = blockIdx.x >> 11, c = blockIdx.x & (KCL - 1);
    __shared__ float sbE[128];
    __shared__ uint4 As[128 * 8];
    __shared__ int permL[128];
    __shared__ float redd[256], redn[256];
    bn_sb(stats + (size_t)(2 * l + 1) * 128, proj_g + l * 64, proj_b + l * 64, n, sbE);
    int t = threadIdx.x, lane = t & 63, w = t >> 6;
    int arow = t >> 1, ah = t & 1;
    const int l15 = lane & 15, lg = lane >> 4;
    int rowA0 = w * 32 + l15, rowA1 = rowA0 + 16;
    const ushort* C = C3 + (size_t)l * n * 64;
    const ushort* WmP = wt64 + (size_t)(6 + l) * 4096;
    float gm = decf(gmax[l]);
    int o = offs[l * KCL + c], m = cnts[l * KCL + c];
    float accd[4] = {0.f, 0.f, 0.f, 0.f}, accn[4] = {0.f, 0.f, 0.f, 0.f};

    for (int ch = 0; ch < m; ch += 128) {
        int j = ch + arow;
        int gi = (j < m) ? perm[o + j] : -1;
        __syncthreads();   // prior-iter As/permL reads complete
        stage_a_gather(feat16, As, gi, arow, ah);
        if (ah == 0) permL[arow] = gi;
        __syncthreads();
        f4v accE[2][4];
#pragma unroll
        for (int rf = 0; rf < 2; ++rf)
#pragma unroll
            for (int nf = 0; nf < 4; ++nf)
#pragma unroll
                for (int q = 0; q < 4; ++q) accE[rf][nf][q] = 0.f;
        mfma_tileG(As, WmP, 64, 0, rowA0, rowA1, rowA0 & 7, rowA1 & 7, l15, lg, accE);
#pragma unroll
        for (int rf = 0; rf < 2; ++rf)
#pragma unroll
            for (int q = 0; q < 4; ++q) {
                int jl = w * 32 + rf * 16 + lg * 4 + q;   // local row in [0,128)
                if (ch + jl < m) {
                    int row = permL[jl];
                    const ushort* Crow = C + (size_t)row * 64;
#pragma unroll
                    for (int nf = 0; nf < 4; ++nf) {
                        int col = nf * 16 + l15;
                        float d = expf(bf2f(Crow[col]) - gm);
                        float pf = lrelu(accE[rf][nf][q] * sbE[col] + sbE[64 + col]);
                        accd[nf] += d;
                        accn[nf] += pf * d;
                    }
                }
            }
    }
#pragma unroll
    for (int nf = 0; nf < 4; ++nf) {
        float s = accd[nf], s2 = accn[nf];
        s += __shfl_xor(s, 16); s += __shfl_xor(s, 32);
        s2 += __shfl_xor(s2, 16); s2 += __shfl_xor(s2, 32);
        if (lg == 0) {
            redd[w * 64 + nf * 16 + l15] = s;
            redn[w * 64 + nf * 16 + l15] = s2;
        }
    }
    __syncthreads();
    if (t < 64) {
        float sd = redd[t] + redd[64 + t] + redd[128 + t] + redd[192 + t];
        float sn = redn[t] + redn[64 + t] + redn[128 + t] + redn[192 + t];
        seg3[((size_t)l * KCL + c) * 64 + t] = sn / (sd + 1e-6f);
    }
}

// ================= fuse GEMM: t3 = [bnlrelu(P3) | blend] @ Wf(128x64), bf16 out + stats =================
__global__ __launch_bounds__(256) void fuse_mfma(const ushort* __restrict__ P3, const double* __restrict__ statsP,
                                                 const float* __restrict__ gg, const float* __restrict__ bb, int n,
                                                 const float* __restrict__ adp, const int* __restrict__ clusters,
                                                 const float* __restrict__ s3_0, const float* __restrict__ s3_1,
                                                 const float* __restrict__ s3_2, const ushort* __restrict__ WfT,
                                                 ushort* __restrict__ out, double* __restrict__ stats_out) {
    __shared__ uint4 As[128 * 8];
    __shared__ float sb[128];
    int t = threadIdx.x, lane = t & 63, w = t >> 6;
    int rb = blockIdx.x * 128;
    int arow = t >> 1, ah = t & 1;
    const int l15 = lane & 15, lg = lane >> 4;

    bn_sb(statsP, gg, bb, n, sb);

    f4v acc[2][4];
#pragma unroll
    for (int rf = 0; rf < 2; ++rf)
#pragma unroll
        for (int nf = 0; nf < 4; ++nf)
#pragma unroll
            for (int q = 0; q < 4; ++q) acc[rf][nf][q] = 0.f;

    int rowA0 = w * 32 + l15, rowA1 = rowA0 + 16;
    int row = rb + arow;

    for (int p = 0; p < 2; ++p) {
        if (p) __syncthreads();
        float vals[32];
        if (row < n) {
            if (p == 0) {
                const U8* s8p = (const U8*)(P3 + (size_t)row * 64 + ah * 32);
#pragma unroll
                for (int c = 0; c < 4; ++c) {
                    U8 u = s8p[c];
#pragma unroll
                    for (int e = 0; e < 8; ++e) {
                        int col = ah * 32 + c * 8 + e;
                        vals[c * 8 + e] = lrelu(bf2f(u.u[e]) * sb[col] + sb[64 + col]);
                    }
                }
            } else {
                float a0 = adp[(size_t)row * 3 + 0], a1 = adp[(size_t)row * 3 + 1], a2 = adp[(size_t)row * 3 + 2];
                const float* r0 = s3_0 + (size_t)clusters[row] * 64 + ah * 32;
                const float* r1 = s3_1 + (size_t)clusters[(size_t)n + row] * 64 + ah * 32;
                const float* r2 = s3_2 + (size_t)clusters[2 * (size_t)n + row] * 64 + ah * 32;
#pragma unroll
                for (int i = 0; i < 32; ++i) vals[i] = a0 * r0[i] + a1 * r1[i] + a2 * r2[i];
            }
        } else {
#pragma unroll
            for (int i = 0; i < 32; ++i) vals[i] = 0.f;
        }
        stage_a_vals(vals, As, arow, ah);
        __syncthreads();
        mfma_tileG(As, WfT, 128, p * 64, rowA0, rowA1, rowA0 & 7, rowA1 & 7, l15, lg, acc);
    }
    int base = rb + w * 32;
#pragma unroll
    for (int rf = 0; rf < 2; ++rf)
#pragma unroll
        for (int nf = 0; nf < 4; ++nf)
#pragma unroll
            for (int q = 0; q < 4; ++q) {
                int r = base + rf * 16 + lg * 4 + q;
                if (r < n) out[(size_t)r * 64 + nf * 16 + l15] = f2bf(acc[rf][nf][q]);
            }
    __syncthreads();
    float* sp = (float*)As;
    int gidx = w * 4 + lg;
#pragma unroll
    for (int nf = 0; nf < 4; ++nf) {
        int col = nf * 16 + l15;
        float s = 0.f, s2 = 0.f;
#pragma unroll
        for (int rf = 0; rf < 2; ++rf)
#pragma unroll
            for (int q = 0; q < 4; ++q) {
                int r = base + rf * 16 + lg * 4 + q;
                if (r < n) {
                    float v = acc[rf][nf][q];
                    s += v;
                    s2 += v * v;
                }
            }
        sp[gidx * 64 + col] = s;
        sp[1024 + gidx * 64 + col] = s2;
    }
    __syncthreads();
    if (t < 64) {
        float s = 0.f, s2 = 0.f;
#pragma unroll
        for (int i = 0; i < 16; ++i) {
            s += sp[i * 64 + t];
            s2 += sp[1024 + i * 64 + t];
        }
        atomicAdd(&stats_out[t], (double)s);
        atomicAdd(&stats_out[64 + t], (double)s2);
    }
}

// ================= submanifold conv: A+W LDS double-buffered + zero-skip =================
__global__ __launch_bounds__(256) void subm_conv_db(const ushort* __restrict__ fin, const int* __restrict__ nbr,
                                                    const ushort* __restrict__ Wt, ushort* __restrict__ vout,
                                                    int n, double* __restrict__ stats_out) {
    __shared__ uint4 As[2][128 * 8];
    __shared__ uint4 Ws[2][64 * 8];
    int t = threadIdx.x;
    int lane = t & 63, w = t >> 6;
    int rb = blockIdx.x * 128;
    int arow = t >> 1, ah = t & 1;
    int wrow = t >> 2, wq = t & 3;
    const int l15 = lane & 15, lg = lane >> 4;
    int rowA0 = w * 32 + l15, rowA1 = rowA0 + 16;
    int swA0 = rowA0 & 7, swA1 = rowA1 & 7;
    const bool rowok = (rb + arow) < n;
    const int swa = arow & 7, sww = wrow & 7;

    f4v acc[2][4];
#pragma unroll
    for (int rf = 0; rf < 2; ++rf)
#pragma unroll
        for (int nf = 0; nf < 4; ++nf)
#pragma unroll
            for (int q = 0; q < 4; ++q) acc[rf][nf][q] = 0.f;

    bool fc0, fc1, wzc, wzn = false;
    {
        int gi = rowok ? nbr[rb + arow] : -1;
        uint4 v0 = {0, 0, 0, 0}, v1 = v0, v2 = v0, v3 = v0;
        if (gi >= 0) {
            const uint4* src = (const uint4*)(fin + (size_t)gi * 64) + ah * 4;
            v0 = src[0]; v1 = src[1]; v2 = src[2]; v3 = src[3];
        }
        unsigned long long bal = __ballot(gi >= 0);
        fc0 = (bal & 0xffffffffull) != 0ull;
        fc1 = (bal >> 32) != 0ull;
        wzc = (gi < 0);
        uint4* dst = As[0] + arow * 8;
        dst[(ah * 4 + 0) ^ swa] = v0;
        dst[(ah * 4 + 1) ^ swa] = v1;
        dst[(ah * 4 + 2) ^ swa] = v2;
        dst[(ah * 4 + 3) ^ swa] = v3;
        const uint4* ws = (const uint4*)(Wt + (size_t)wrow * 64);
        uint4* wdst = Ws[0] + wrow * 8;
        wdst[wq ^ sww] = ws[wq];
        wdst[(wq + 4) ^ sww] = ws[wq + 4];
    }
    int gi_next = rowok ? nbr[(size_t)n + rb + arow] : -1;
    int cur = 0;

    for (int k = 0; k < 27; ++k) {
        uint4 a0, a1, a2, a3, w0, w1;
        bool fn0 = false, fn1 = false, missn = true;
        if (k < 26) {
            missn = (gi_next < 0);
            a0 = a1 = a2 = a3 = (uint4){0, 0, 0, 0};
            if (!missn) {
                const uint4* src = (const uint4*)(fin + (size_t)gi_next * 64) + ah * 4;
                a0 = src[0]; a1 = src[1]; a2 = src[2]; a3 = src[3];
            }
            unsigned long long bal = __ballot(!missn);
            fn0 = (bal & 0xffffffffull) != 0ull;
            fn1 = (bal >> 32) != 0ull;
            const uint4* ws = (const uint4*)(Wt + (size_t)(k + 1) * 4096 + (size_t)wrow * 64);
            w0 = ws[wq];
            w1 = ws[wq + 4];
            if (k < 25) gi_next = rowok ? nbr[(size_t)(k + 2) * n + rb + arow] : -1;
        }
        __syncthreads();
        if (fc0 | fc1) {
            const s8v* Av = (const s8v*)As[cur];
            const s8v* Wv = (const s8v*)Ws[cur];
#pragma unroll
            for (int kb = 0; kb < 2; ++kb) {
                int gch = kb * 4 + lg;
                s8v bfr[4];
#pragma unroll
                for (int nf = 0; nf < 4; ++nf) {
                    int col = nf * 16 + l15;
                    bfr[nf] = Wv[col * 8 + (gch ^ (col & 7))];
                }
                if (fc0) {
                    s8v av0 = Av[rowA0 * 8 + (gch ^ swA0)];
#pragma unroll
                    for (int nf = 0; nf < 4; ++nf)
                        acc[0][nf] = __builtin_amdgcn_mfma_f32_16x16x32_bf16(av0, bfr[nf], acc[0][nf], 0, 0, 0);
                }
                if (fc1) {
                    s8v av1 = Av[rowA1 * 8 + (gch ^ swA1)];
#pragma unroll
                    for (int nf = 0; nf < 4; ++nf)
                        acc[1][nf] = __builtin_amdgcn_mfma_f32_16x16x32_bf16(av1, bfr[nf], acc[1][nf], 0, 0, 0);
                }
            }
        }
        if (k < 26) {
            if (!(missn && wzn)) {
                uint4* dst = As[cur ^ 1] + arow * 8;
                dst[(ah * 4 + 0) ^ swa] = a0;
                dst[(ah * 4 + 1) ^ swa] = a1;
                dst[(ah * 4 + 2) ^ swa] = a2;
                dst[(ah * 4 + 3) ^ swa] = a3;
            }
            uint4* wdst = Ws[cur ^ 1] + wrow * 8;
            wdst[wq ^ sww] = w0;
            wdst[(wq + 4) ^ sww] = w1;
            cur ^= 1;
            bool nw = wzc;
            wzc = missn;
            wzn = nw;
            fc0 = fn0;
            fc1 = fn1;
        }
    }
    int base = rb + w * 32;
#pragma unroll
    for (int rf = 0; rf < 2; ++rf)
#pragma unroll
        for (int nf = 0; nf < 4; ++nf)
#pragma unroll
            for (int q = 0; q < 4; ++q) {
                int r = base + rf * 16 + lg * 4 + q;
                if (r < n) vout[(size_t)r * 64 + nf * 16 + l15] = f2bf(acc[rf][nf][q]);
            }
    __syncthreads();
    float* sp = (float*)As[0];
    int gidx = w * 4 + lg;
#pragma unroll
    for (int nf = 0; nf < 4; ++nf) {
        int col = nf * 16 + l15;
        float s = 0.f, s2 = 0.f;
#pragma unroll
        for (int rf = 0; rf < 2; ++rf)
#pragma unroll
            for (int q = 0; q < 4; ++q) {
                int r = base + rf * 16 + lg * 4 + q;
                if (r < n) {
                    float v = acc[rf][nf][q];
                    s += v;
                    s2 += v * v;
                }
            }
        sp[gidx * 64 + col] = s;
        sp[1024 + gidx * 64 + col] = s2;
    }
    __syncthreads();
    if (t < 64) {
        float s = 0.f, s2 = 0.f;
#pragma unroll
        for (int i = 0; i < 16; ++i) {
            s += sp[i * 64 + t];
            s2 += sp[1024 + i * 64 + t];
        }
        atomicAdd(&stats_out[t], (double)s);
        atomicAdd(&stats_out[64 + t], (double)s2);
    }
}

// ---------------- f16 = bf16(lrelu(bn(t3)) + feat) ----------------
__global__ __launch_bounds__(256) void addfeat_kernel(const ushort* __restrict__ t3, const double* __restrict__ stats,
                                                      const float* __restrict__ g, const float* __restrict__ b,
                                                      const float* __restrict__ feat, ushort* __restrict__ f16,
                                                      int n) {
    __shared__ float sb[128];
    bn_sb(stats, g, b, n, sb);
    long total4 = (long)n * 16;
    for (long i = (long)blockIdx.x * 256 + threadIdx.x; i < total4; i += (long)gridDim.x * 256) {
        int c0 = (int)(i & 15) * 4;
        ushort4 xv = ((const ushort4*)t3)[i];
        float4 fz = ((const float4*)feat)[i];
        ushort4 u;
        u.x = f2bf(lrelu(bf2f(xv.x) * sb[c0 + 0] + sb[64 + c0 + 0]) + fz.x);
        u.y = f2bf(lrelu(bf2f(xv.y) * sb[c0 + 1] + sb[64 + c0 + 1]) + fz.y);
        u.z = f2bf(lrelu(bf2f(xv.z) * sb[c0 + 2] + sb[64 + c0 + 2]) + fz.z);
        u.w = f2bf(lrelu(bf2f(xv.w) * sb[c0 + 3] + sb[64 + c0 + 3]) + fz.w);
        ((ushort4*)f16)[i] = u;
    }
}

// ---------------- o16 = bf16(lrelu(bn(v16))) ----------------
__global__ __launch_bounds__(256) void bnlrelu_tobf16_kernel(const ushort* __restrict__ v,
                                                             const double* __restrict__ stats,
                                                             const float* __restrict__ g, const float* __restrict__ b,
                                                             ushort* __restrict__ o16, int n) {
    __shared__ float sb[128];
    bn_sb(stats, g, b, n, sb);
    long total4 = (long)n * 16;
    for (long i = (long)blockIdx.x * 256 + threadIdx.x; i < total4; i += (long)gridDim.x * 256) {
        int c0 = (int)(i & 15) * 4;
        ushort4 xv = ((const ushort4*)v)[i];
        ushort4 u;
        u.x = f2bf(lrelu(bf2f(xv.x) * sb[c0 + 0] + sb[64 + c0 + 0]));
        u.y = f2bf(lrelu(bf2f(xv.y) * sb[c0 + 1] + sb[64 + c0 + 1]));
        u.z = f2bf(lrelu(bf2f(xv.z) * sb[c0 + 2] + sb[64 + c0 + 2]));
        u.w = f2bf(lrelu(bf2f(xv.w) * sb[c0 + 3] + sb[64 + c0 + 3]));
        ((ushort4*)o16)[i] = u;
    }
}

// ---------------- out = lrelu(bn(w16) + f16) ----------------
__global__ __launch_bounds__(256) void final_kernel(const ushort* __restrict__ w16, const double* __restrict__ stats,
                                                    const float* __restrict__ g, const float* __restrict__ b,
                                                    const ushort* __restrict__ f16, float* __restrict__ out, int n) {
    __shared__ float sb[128];
    bn_sb(stats, g, b, n, sb);
    long total4 = (long)n * 16;
    for (long i = (long)blockIdx.x * 256 + threadIdx.x; i < total4; i += (long)gridDim.x * 256) {
        int c0 = (int)(i & 15) * 4;
        ushort4 xv = ((const ushort4*)w16)[i];
        ushort4 u = ((const ushort4*)f16)[i];
        float4 y;
        y.x = lrelu(bf2f(xv.x) * sb[c0 + 0] + sb[64 + c0 + 0] + bf2f(u.x));
        y.y = lrelu(bf2f(xv.y) * sb[c0 + 1] + sb[64 + c0 + 1] + bf2f(u.y));
        y.z = lrelu(bf2f(xv.z) * sb[c0 + 2] + sb[64 + c0 + 2] + bf2f(u.z));
        y.w = lrelu(bf2f(xv.w) * sb[c0 + 3] + sb[64 + c0 + 3] + bf2f(u.w));
        ((float4*)out)[i] = y;
    }
}

extern "C" void kernel_launch(void* const* d_in, const int* in_sizes, int n_in,
                              void* d_out, int out_size, void* d_ws, size_t ws_size,
                              hipStream_t stream) {
    const float* feat = (const float*)d_in[0];
    const float* lw_W = (const float*)d_in[1];
    const float* lw_g = (const float*)d_in[2];
    const float* lw_b = (const float*)d_in[3];
    const float* w_W = (const float*)d_in[4];
    const float* proj_W = (const float*)d_in[5];
    const float* proj_g = (const float*)d_in[6];
    const float* proj_b = (const float*)d_in[7];
    const float* adaptive_W = (const float*)d_in[8];
    const float* fuse_W = (const float*)d_in[9];
    const float* fuse_g = (const float*)d_in[10];
    const float* fuse_b = (const float*)d_in[11];
    const float* conv1_W = (const float*)d_in[12];
    const float* bn1_g = (const float*)d_in[13];
    const float* bn1_b = (const float*)d_in[14];
    const float* conv2_W = (const float*)d_in[15];
    const float* bn2_g = (const float*)d_in[16];
    const float* bn2_b = (const float*)d_in[17];
    const int* clusters = (const int*)d_in[18];
    const int* nbr = (const int*)d_in[19];

    const int n = in_sizes[0] / 64;

    char* ws = (char*)d_ws;
    size_t off = 0;
    auto alloc = [&](size_t bytes) -> size_t {
        size_t o = off;
        off = (off + bytes + 255) & ~(size_t)255;
        return o;
    };
    // zeroed region
    size_t cnt_off = alloc((size_t)3 * KCL * 4);
    size_t stats_off = alloc((size_t)10 * 128 * 8);
    size_t gmax_off = alloc(16);
    size_t zbytes = off;
    // non-zeroed
    size_t offs_off = alloc((size_t)3 * KCL * 4);
    size_t cur_off = alloc((size_t)3 * KCL * 4);
    size_t perm_off = alloc((size_t)3 * n * 4);
    size_t mean_off = alloc((size_t)3 * KCL * 64 * 4);
    size_t mw_off = alloc((size_t)3 * KCL * 64 * 4);
    size_t seg3_off = alloc((size_t)3 * KCL * 64 * 4);
    size_t adp_off = alloc((size_t)n * 3 * 4);
    size_t feat16_off = alloc((size_t)n * 64 * 2);
    size_t ra_off = alloc((size_t)3 * n * 64 * 2);   // A0-2 -> C0-2 in place; later t3/fbuf16/c1out
    size_t re_off = alloc((size_t)2 * n * 64 * 2);   // cbuf, c2out
    size_t wt64_off = alloc((size_t)64 * 4096 * 2);
    size_t wfT_off = alloc((size_t)8192 * 2);

    int* cnts = (int*)(ws + cnt_off);
    double* stats = (double*)(ws + stats_off);
    unsigned* gmax = (unsigned*)(ws + gmax_off);
    int* offs = (int*)(ws + offs_off);
    int* cursor = (int*)(ws + cur_off);
    int* perm = (int*)(ws + perm_off);
    float* meanB3 = (float*)(ws + mean_off);
    float* MW3 = (float*)(ws + mw_off);
    float* seg3 = (float*)(ws + seg3_off);
    float* adp = (float*)(ws + adp_off);
    ushort* feat16 = (ushort*)(ws + feat16_off);
    ushort* RA = (ushort*)(ws + ra_off);
    ushort* RE = (ushort*)(ws + re_off);
    ushort* wt64 = (ushort*)(ws + wt64_off);
    ushort* wfT = (ushort*)(ws + wfT_off);
    float* outp = (float*)d_out;

    // aliases (sequential liveness on one stream)
    ushort* A3 = RA;                                  // A0-2, then C0-2 in place
    ushort* P3 = (ushort*)d_out + (size_t)n * 64;     // d_out high half as bf16 scratch
    ushort* t3buf = RA;                               // after seg3g (C dead)
    ushort* fbuf16 = RA + (size_t)n * 64;
    ushort* c1out = RA + (size_t)2 * n * 64;
    ushort* cbuf = RE;
    ushort* c2out = RE + (size_t)n * 64;

    const ushort* wW16 = wt64 + (size_t)3 * 4096;
    const ushort* conv1W16 = wt64 + (size_t)10 * 4096;
    const ushort* conv2W16 = wt64 + (size_t)37 * 4096;

    hipMemsetAsync(d_ws, 0, zbytes, stream);

    const int GEMM_BLK = (n + 127) / 128;
    const int EW_BLK = 2048;

    prep_wt64<<<64, 256, 0, stream>>>(lw_W, w_W, proj_W, conv1_W, conv2_W, wt64);
    prep_fuse<<<1, 256, 0, stream>>>(fuse_W, wfT);
    adp_cvt_kernel<<<1024, 256, 0, stream>>>(feat, adaptive_W, adp, feat16, n);

    hist3_kernel<<<384, 256, 0, stream>>>(clusters, cnts, n);
    scan_kernel<<<3, 256, 0, stream>>>(cnts, offs, cursor, n);
    scatter_kernel<<<1024, 256, 0, stream>>>(clusters, cursor, perm, n);

    // stats for all 7 products; write only A0-2 (RA) and P3 (d_out high)
    mega7_gemm<<<GEMM_BLK, 256, 0, stream>>>(feat16, wt64,
                                             A3, A3 + (size_t)n * 64, A3 + (size_t)2 * n * 64,
                                             P3, n, stats);
    // per-cluster means of bnlrelu(A_l)
    reduce_mean3_kernel<<<3 * KCL, 256, 0, stream>>>(A3, stats, lw_g, lw_b, n, cnts, offs, perm, meanB3);
    // MW_l = meanB_l @ wW_l
    mw3_gemm<<<3 * 16, 256, 0, stream>>>(meanB3, wW16, MW3);
    // C_l = bnlrelu(A_l) @ wW_l - MW_l[clus]  (in place over A_l) + gmax_l
    cgemm3<<<3 * GEMM_BLK, 256, 0, stream>>>(A3, wW16, MW3, clusters, stats, lw_g, lw_b, gmax, n, GEMM_BLK);
    // seg3_l[c] = softmax-pool: C gathered from C3, E recomputed via gather(feat16)@proj_l
    seg3g_kernel<<<3 * KCL, 256, 0, stream>>>(A3, feat16, wt64, stats, proj_g, proj_b, n, gmax,
                                              cnts, offs, perm, seg3);

    // t3 = [bnlrelu(P3) | blend(adp,seg3)] @ fuse_W + stats(7)
    fuse_mfma<<<GEMM_BLK, 256, 0, stream>>>(P3, stats + 6 * 128, proj_g + 192, proj_b + 192, n,
                                            adp, clusters,
                                            seg3, seg3 + (size_t)KCL * 64, seg3 + (size_t)2 * KCL * 64,
                                            wfT, t3buf, stats + 7 * 128);
    // f = lrelu(bn(t3)) + feat  (bf16)
    addfeat_kernel<<<EW_BLK, 256, 0, stream>>>(t3buf, stats + 7 * 128, fuse_g, fuse_b, feat, fbuf16, n);

    // conv1 -> c1out (+stats 8); bn1+lrelu -> cbuf
    subm_conv_db<<<GEMM_BLK, 256, 0, stream>>>(fbuf16, nbr, conv1W16, c1out, n, stats + 8 * 128);
    bnlrelu_tobf16_kernel<<<EW_BLK, 256, 0, stream>>>(c1out, stats + 8 * 128, bn1_g, bn1_b, cbuf, n);

    // conv2 -> c2out (+stats 9); out = lrelu(bn2 + f)
    subm_conv_db<<<GEMM_BLK, 256, 0, stream>>>(cbuf, nbr, conv2W16, c2out, n, stats + 9 * 128);
    final_kernel<<<EW_BLK, 256, 0, stream>>>(c2out, stats + 9 * 128, bn2_g, bn2_b, fbuf16, outp, n);
}

// Round 15
// 577.346 us; speedup vs baseline: 1.0524x; 1.0205x over previous
//
#include <hip/hip_runtime.h>
#include <hip/hip_bf16.h>
#include <math.h>

#define KCL 2048
#define LRELU_NEG 0.01f
#define EPSBN 1e-5f

using s8v = __attribute__((ext_vector_type(8))) short;   // 8 bf16 (4 VGPRs)
using f4v = __attribute__((ext_vector_type(4))) float;   // MFMA accumulator

union U8 { ushort u[8]; uint4 v; };

__device__ __forceinline__ float lrelu(float x) { return x > 0.f ? x : LRELU_NEG * x; }
__device__ __forceinline__ ushort f2bf(float f) {
    __hip_bfloat16 h = __float2bfloat16(f);
    return *reinterpret_cast<ushort*>(&h);
}
__device__ __forceinline__ float bf2f(ushort u) { return __uint_as_float(((unsigned)u) << 16); }

// monotonic float->uint encoding for atomicMax over mixed-sign floats
__device__ __forceinline__ unsigned encf(float f) {
    unsigned u = __float_as_uint(f);
    return (u & 0x80000000u) ? ~u : (u | 0x80000000u);
}
__device__ __forceinline__ float decf(unsigned u) {
    return __uint_as_float((u & 0x80000000u) ? (u & 0x7fffffffu) : ~u);
}

// finalize BN stats into LDS scale/bias: y = x*sb[col] + sb[64+col]
__device__ __forceinline__ void bn_sb(const double* __restrict__ stats, const float* __restrict__ g,
                                      const float* __restrict__ b, int n, float* sb) {
    int t = threadIdx.x;
    if (t < 64) {
        float mean = (float)(stats[t] / n);
        float ex2 = (float)(stats[64 + t] / n);
        float var = fmaxf(ex2 - mean * mean, 0.f);
        float rstd = rsqrtf(var + EPSBN);
        float sc = rstd * g[t];
        sb[t] = sc;
        sb[64 + t] = b[t] - mean * sc;
    }
    __syncthreads();
}

// ---------------- shared MFMA helpers ----------------
__device__ __forceinline__ void mfma_tile(const uint4* As, const uint4* Ws, int rowA0, int rowA1,
                                          int swA0, int swA1, int l15, int lg, f4v acc[2][4]) {
    const s8v* Av = (const s8v*)As;
    const s8v* Wv = (const s8v*)Ws;
#pragma unroll
    for (int kb = 0; kb < 2; ++kb) {
        int gch = kb * 4 + lg;
        s8v a0 = Av[rowA0 * 8 + (gch ^ swA0)];
        s8v a1 = Av[rowA1 * 8 + (gch ^ swA1)];
#pragma unroll
        for (int nf = 0; nf < 4; ++nf) {
            int col = nf * 16 + l15;
            s8v bf = Wv[col * 8 + (gch ^ (col & 7))];
            acc[0][nf] = __builtin_amdgcn_mfma_f32_16x16x32_bf16(a0, bf, acc[0][nf], 0, 0, 0);
            acc[1][nf] = __builtin_amdgcn_mfma_f32_16x16x32_bf16(a1, bf, acc[1][nf], 0, 0, 0);
        }
    }
}

// MFMA over a staged A tile with B fragments loaded straight from global (L1/L2-hot).
// Wmat layout: row = output col, contiguous K, row stride ws elements, + koff.
__device__ __forceinline__ void mfma_tileG(const uint4* As, const ushort* Wmat, int ws, int koff,
                                           int rowA0, int rowA1, int swA0, int swA1,
                                           int l15, int lg, f4v acc[2][4]) {
    const s8v* Av = (const s8v*)As;
#pragma unroll
    for (int kb = 0; kb < 2; ++kb) {
        int gch = kb * 4 + lg;
        s8v a0 = Av[rowA0 * 8 + (gch ^ swA0)];
        s8v a1 = Av[rowA1 * 8 + (gch ^ swA1)];
#pragma unroll
        for (int nf = 0; nf < 4; ++nf) {
            int col = nf * 16 + l15;
            s8v bf = *(const s8v*)(Wmat + (size_t)col * ws + koff + gch * 8);
            acc[0][nf] = __builtin_amdgcn_mfma_f32_16x16x32_bf16(a0, bf, acc[0][nf], 0, 0, 0);
            acc[1][nf] = __builtin_amdgcn_mfma_f32_16x16x32_bf16(a1, bf, acc[1][nf], 0, 0, 0);
        }
    }
}

__device__ __forceinline__ void stage_a_bf16(const ushort* S, uint4* As, int row, int n, int arow, int ah) {
    uint4 c0 = {0, 0, 0, 0}, c1 = c0, c2 = c0, c3 = c0;
    if (row < n) {
        const uint4* s = (const uint4*)(S + (size_t)row * 64) + ah * 4;
        c0 = s[0]; c1 = s[1]; c2 = s[2]; c3 = s[3];
    }
    int sw = arow & 7;
    uint4* dst = As + arow * 8;
    dst[(ah * 4 + 0) ^ sw] = c0;
    dst[(ah * 4 + 1) ^ sw] = c1;
    dst[(ah * 4 + 2) ^ sw] = c2;
    dst[(ah * 4 + 3) ^ sw] = c3;
}

__device__ __forceinline__ void stage_a_vals(const float* vals, uint4* As, int arow, int ah) {
    int sw = arow & 7;
    uint4* dst = As + arow * 8;
#pragma unroll
    for (int c = 0; c < 4; ++c) {
        U8 u;
#pragma unroll
        for (int e = 0; e < 8; ++e) u.u[e] = f2bf(vals[c * 8 + e]);
        dst[(ah * 4 + c) ^ sw] = u.v;
    }
}

// ---------------- weight prep: 64 matrices of 64x64, transposed -> bf16 ----------------
__global__ __launch_bounds__(256) void prep_wt64(const float* __restrict__ lw, const float* __restrict__ wW,
                                                 const float* __restrict__ proj, const float* __restrict__ c1,
                                                 const float* __restrict__ c2, ushort* __restrict__ wt) {
    int bk = blockIdx.x;
    const float* W;
    if (bk < 3) W = lw + (size_t)bk * 4096;
    else if (bk < 6) W = wW + (size_t)(bk - 3) * 4096;
    else if (bk < 10) W = proj + (size_t)(bk - 6) * 4096;
    else if (bk < 37) W = c1 + (size_t)(bk - 10) * 4096;
    else W = c2 + (size_t)(bk - 37) * 4096;
    ushort* o = wt + (size_t)bk * 4096;
    for (int i = threadIdx.x; i < 4096; i += 256) {
        int kk = i >> 6, cc = i & 63;
        o[cc * 64 + kk] = f2bf(W[i]);
    }
}

__global__ __launch_bounds__(256) void prep_fuse(const float* __restrict__ Wf, ushort* __restrict__ o) {
    for (int i = threadIdx.x; i < 8192; i += 256) {
        int kk = i >> 6, cc = i & 63;
        o[cc * 128 + kk] = f2bf(Wf[i]);
    }
}

// ---------------- adaptive weights + fp32->bf16 convert (one pass over feat) ----------------
__global__ __launch_bounds__(256) void adp_cvt_kernel(const float* __restrict__ feat, const float* __restrict__ aW,
                                                      float* __restrict__ adp, ushort* __restrict__ feat16, int n) {
    __shared__ float w[192];
    for (int i = threadIdx.x; i < 192; i += 256) w[i] = aW[i];
    __syncthreads();
    for (long row = (long)blockIdx.x * 256 + threadIdx.x; row < n; row += (long)gridDim.x * 256) {
        const float4* fr = (const float4*)(feat + row * 64);
        ushort4* fo = (ushort4*)(feat16 + row * 64);
        float l0 = 0.f, l1 = 0.f, l2 = 0.f;
#pragma unroll
        for (int q = 0; q < 16; ++q) {
            float4 x = fr[q];
            int k = q * 4;
            l0 += x.x * w[k * 3 + 0] + x.y * w[k * 3 + 3] + x.z * w[k * 3 + 6] + x.w * w[k * 3 + 9];
            l1 += x.x * w[k * 3 + 1] + x.y * w[k * 3 + 4] + x.z * w[k * 3 + 7] + x.w * w[k * 3 + 10];
            l2 += x.x * w[k * 3 + 2] + x.y * w[k * 3 + 5] + x.z * w[k * 3 + 8] + x.w * w[k * 3 + 11];
            ushort4 u;
            u.x = f2bf(x.x); u.y = f2bf(x.y); u.z = f2bf(x.z); u.w = f2bf(x.w);
            fo[q] = u;
        }
        float m = fmaxf(l0, fmaxf(l1, l2));
        float e0 = expf(l0 - m), e1 = expf(l1 - m), e2 = expf(l2 - m);
        float inv = 1.f / (e0 + e1 + e2);
        adp[row * 3 + 0] = e0 * inv;
        adp[row * 3 + 1] = e1 * inv;
        adp[row * 3 + 2] = e2 * inv;
    }
}

// ---------------- cluster histogram, all 3 levels ----------------
__global__ __launch_bounds__(256) void hist3_kernel(const int* __restrict__ clusters, int* __restrict__ cnt,
                                                    int n) {
    __shared__ int h[KCL];
    int l = blockIdx.x % 3;
    int nb = gridDim.x / 3, bi = blockIdx.x / 3;
    for (int i = threadIdx.x; i < KCL; i += 256) h[i] = 0;
    __syncthreads();
    const int* cl = clusters + (size_t)l * n;
    for (long i = (long)bi * 256 + threadIdx.x; i < n; i += (long)nb * 256)
        atomicAdd(&h[cl[i]], 1);
    __syncthreads();
    for (int i = threadIdx.x; i < KCL; i += 256) {
        int v = h[i];
        if (v) atomicAdd(&cnt[l * KCL + i], v);
    }
}

// ---------------- exclusive scan -> absolute offsets + cursor ----------------
__global__ __launch_bounds__(256) void scan_kernel(const int* __restrict__ cnt, int* __restrict__ off,
                                                   int* __restrict__ cursor, int n) {
    int l = blockIdx.x;
    const int* c = cnt + l * KCL;
    __shared__ int part[256];
    __shared__ int pref[256];
    int t = threadIdx.x;
    int base = t * 8;
    int v[8];
    int s = 0;
#pragma unroll
    for (int j = 0; j < 8; ++j) { v[j] = c[base + j]; s += v[j]; }
    part[t] = s;
    __syncthreads();
    if (t == 0) {
        int acc = 0;
        for (int i = 0; i < 256; ++i) { pref[i] = acc; acc += part[i]; }
    }
    __syncthreads();
    int acc = pref[t] + l * n;
#pragma unroll
    for (int j = 0; j < 8; ++j) {
        off[l * KCL + base + j] = acc;
        cursor[l * KCL + base + j] = acc;
        acc += v[j];
    }
}

// ---------------- scatter rows into cluster-sorted perm ----------------
__global__ __launch_bounds__(256) void scatter_kernel(const int* __restrict__ clusters, int* __restrict__ cursor,
                                                      int* __restrict__ perm, int n) {
    long n3 = (long)n * 3;
    for (long i = (long)blockIdx.x * 256 + threadIdx.x; i < n3; i += (long)gridDim.x * 256) {
        int l = (i >= n) + (i >= 2 * (long)n);
        int c = clusters[i];
        int pos = atomicAdd(&cursor[l * KCL + c], 1);
        perm[pos] = (int)(i - (long)l * n);
    }
}

// ---------------- one GEMM pass over a staged A tile: bf16 out + stats ----------------
__device__ __forceinline__ void mega_one(const uint4* As, float* red, const ushort* Wmat, ushort* out,
                                         double* statp, int n, int rb, int w, int lane, int t) {
    const int l15 = lane & 15, lg = lane >> 4;
    int rowA0 = w * 32 + l15, rowA1 = rowA0 + 16;
    f4v acc[2][4];
#pragma unroll
    for (int rf = 0; rf < 2; ++rf)
#pragma unroll
        for (int nf = 0; nf < 4; ++nf)
#pragma unroll
            for (int q = 0; q < 4; ++q) acc[rf][nf][q] = 0.f;
    mfma_tileG(As, Wmat, 64, 0, rowA0, rowA1, rowA0 & 7, rowA1 & 7, l15, lg, acc);
    int base = rb + w * 32;
#pragma unroll
    for (int rf = 0; rf < 2; ++rf)
#pragma unroll
        for (int nf = 0; nf < 4; ++nf)
#pragma unroll
            for (int q = 0; q < 4; ++q) {
                int r = base + rf * 16 + lg * 4 + q;
                if (r < n) out[(size_t)r * 64 + nf * 16 + l15] = f2bf(acc[rf][nf][q]);
            }
#pragma unroll
    for (int nf = 0; nf < 4; ++nf) {
        float s = 0.f, s2 = 0.f;
#pragma unroll
        for (int rf = 0; rf < 2; ++rf)
#pragma unroll
            for (int q = 0; q < 4; ++q) {
                int r = base + rf * 16 + lg * 4 + q;
                if (r < n) {
                    float v = acc[rf][nf][q];
                    s += v;
                    s2 += v * v;
                }
            }
        s += __shfl_xor(s, 16); s += __shfl_xor(s, 32);
        s2 += __shfl_xor(s2, 16); s2 += __shfl_xor(s2, 32);
        if (lg == 0) {
            red[w * 64 + nf * 16 + l15] = s;
            red[256 + w * 64 + nf * 16 + l15] = s2;
        }
    }
    __syncthreads();
    if (t < 64) {
        float s = red[t] + red[64 + t] + red[128 + t] + red[192 + t];
        float s2 = red[256 + t] + red[320 + t] + red[384 + t] + red[448 + t];
        atomicAdd(&statp[t], (double)s);
        atomicAdd(&statp[64 + t], (double)s2);
    }
    __syncthreads();
}

// ================= mega GEMM: 7 outputs from one staged feat16 tile =================
__global__ __launch_bounds__(256) void mega7_gemm(const ushort* __restrict__ feat16,
                                                  const ushort* __restrict__ wt64,
                                                  ushort* __restrict__ o0, ushort* __restrict__ o1,
                                                  ushort* __restrict__ o2, ushort* __restrict__ o3,
                                                  ushort* __restrict__ o4, ushort* __restrict__ o5,
                                                  ushort* __restrict__ o6,
                                                  int n, double* __restrict__ stats) {
    __shared__ uint4 As[128 * 8];
    __shared__ float red[512];
    int t = threadIdx.x, lane = t & 63, w = t >> 6;
    int rb = blockIdx.x * 128;
    int arow = t >> 1, ah = t & 1;
    stage_a_bf16(feat16, As, rb + arow, n, arow, ah);
    __syncthreads();
    // weights: lw0-2 at slots 0-2 (stats 0,2,4); proj0-3 at slots 6-9 (stats 1,3,5,6)
    mega_one(As, red, wt64 + (size_t)0 * 4096, o0, stats + 0 * 128, n, rb, w, lane, t);
    mega_one(As, red, wt64 + (size_t)1 * 4096, o1, stats + 2 * 128, n, rb, w, lane, t);
    mega_one(As, red, wt64 + (size_t)2 * 4096, o2, stats + 4 * 128, n, rb, w, lane, t);
    mega_one(As, red, wt64 + (size_t)6 * 4096, o3, stats + 1 * 128, n, rb, w, lane, t);
    mega_one(As, red, wt64 + (size_t)7 * 4096, o4, stats + 3 * 128, n, rb, w, lane, t);
    mega_one(As, red, wt64 + (size_t)8 * 4096, o5, stats + 5 * 128, n, rb, w, lane, t);
    mega_one(As, red, wt64 + (size_t)9 * 4096, o6, stats + 6 * 128, n, rb, w, lane, t);
}

// ================= meanB for all 3 levels (block = (level, cluster)) =================
__global__ __launch_bounds__(256) void reduce_mean3_kernel(const ushort* __restrict__ A3,
                                                           const double* __restrict__ stats,
                                                           const float* __restrict__ lw_g,
                                                           const float* __restrict__ lw_b, int n,
                                                           const int* __restrict__ cnts, const int* __restrict__ offs,
                                                           const int* __restrict__ perm,
                                                           float* __restrict__ meanB3) {
    int l = blockIdx.x >> 11, c = blockIdx.x & (KCL - 1);
    const ushort* A = A3 + (size_t)l * n * 64;
    __shared__ float sb[128];
    bn_sb(stats + (size_t)(2 * l) * 128, lw_g + l * 64, lw_b + l * 64, n, sb);
    int t = threadIdx.x, col = t & 63, rg = t >> 6;
    int o = offs[l * KCL + c], m = cnts[l * KCL + c];
    float acc = 0.f;
    float sc = sb[col], bi = sb[64 + col];
    for (int j = rg; j < m; j += 4) {
        int row = perm[o + j];
        acc += lrelu(bf2f(A[(size_t)row * 64 + col]) * sc + bi);
    }
    __shared__ float red[256];
    red[t] = acc;
    __syncthreads();
    if (t < 64) {
        float s = red[t] + red[t + 64] + red[t + 128] + red[t + 192];
        float cf = (float)m;
        if (cf < 1.f) cf = 1.f;
        meanB3[(size_t)l * KCL * 64 + (size_t)c * 64 + col] = s / cf;
    }
}

// ================= MW for all 3 levels: meanB_l @ wW_l =================
__global__ __launch_bounds__(256) void mw3_gemm(const float* __restrict__ meanB3, const ushort* __restrict__ wW16,
                                                float* __restrict__ MW3) {
    __shared__ uint4 As[128 * 8];
    int l = blockIdx.x >> 4, b = blockIdx.x & 15;
    const float* src = meanB3 + (size_t)l * KCL * 64;
    float* out = MW3 + (size_t)l * KCL * 64;
    int t = threadIdx.x, lane = t & 63, w = t >> 6;
    int rb = b * 128;
    int arow = t >> 1, ah = t & 1;
    const int l15 = lane & 15, lg = lane >> 4;
    {
        float vals[32];
        const float4* s = (const float4*)(src + (size_t)(rb + arow) * 64 + ah * 32);
#pragma unroll
        for (int q = 0; q < 8; ++q) {
            float4 x = s[q];
            vals[q * 4 + 0] = x.x; vals[q * 4 + 1] = x.y;
            vals[q * 4 + 2] = x.z; vals[q * 4 + 3] = x.w;
        }
        stage_a_vals(vals, As, arow, ah);
    }
    __syncthreads();
    f4v acc[2][4];
#pragma unroll
    for (int rf = 0; rf < 2; ++rf)
#pragma unroll
        for (int nf = 0; nf < 4; ++nf)
#pragma unroll
            for (int q = 0; q < 4; ++q) acc[rf][nf][q] = 0.f;
    int rowA0 = w * 32 + l15, rowA1 = rowA0 + 16;
    mfma_tileG(As, wW16 + (size_t)l * 4096, 64, 0, rowA0, rowA1, rowA0 & 7, rowA1 & 7, l15, lg, acc);
    int base = rb + w * 32;
#pragma unroll
    for (int rf = 0; rf < 2; ++rf)
#pragma unroll
        for (int nf = 0; nf < 4; ++nf)
#pragma unroll
            for (int q = 0; q < 4; ++q) {
                int r = base + rf * 16 + lg * 4 + q;
                out[(size_t)r * 64 + nf * 16 + l15] = acc[rf][nf][q];
            }
}

// ================= C_l = bnlrelu(A_l) @ wW_l - MW_l[clus], IN PLACE over A, + gmax =================
__global__ __launch_bounds__(256) void cgemm3(ushort* __restrict__ A3io, const ushort* __restrict__ wW16,
                                              const float* __restrict__ MW3, const int* __restrict__ clusters,
                                              const double* __restrict__ stats, const float* __restrict__ lw_g,
                                              const float* __restrict__ lw_b,
                                              unsigned* __restrict__ gmax, int n, int nb) {
    __shared__ uint4 As[128 * 8];
    __shared__ float sb[128];
    int l = blockIdx.x / nb, b = blockIdx.x % nb;
    ushort* A = A3io + (size_t)l * n * 64;
    const float* MW = MW3 + (size_t)l * KCL * 64;
    const int* clus = clusters + (size_t)l * n;
    int t = threadIdx.x, lane = t & 63, w = t >> 6;
    int rb = b * 128;
    int arow = t >> 1, ah = t & 1;
    const int l15 = lane & 15, lg = lane >> 4;

    bn_sb(stats + (size_t)(2 * l) * 128, lw_g + l * 64, lw_b + l * 64, n, sb);
    {
        int row = rb + arow;
        float vals[32];
        if (row < n) {
            const U8* s8p = (const U8*)(A + (size_t)row * 64 + ah * 32);
#pragma unroll
            for (int c = 0; c < 4; ++c) {
                U8 u = s8p[c];
#pragma unroll
                for (int e = 0; e < 8; ++e) {
                    int col = ah * 32 + c * 8 + e;
                    vals[c * 8 + e] = lrelu(bf2f(u.u[e]) * sb[col] + sb[64 + col]);
                }
            }
        } else {
#pragma unroll
            for (int i = 0; i < 32; ++i) vals[i] = 0.f;
        }
        stage_a_vals(vals, As, arow, ah);
    }
    __syncthreads();
    f4v acc[2][4];
#pragma unroll
    for (int rf = 0; rf < 2; ++rf)
#pragma unroll
        for (int nf = 0; nf < 4; ++nf)
#pragma unroll
            for (int q = 0; q < 4; ++q) acc[rf][nf][q] = 0.f;
    int rowA0 = w * 32 + l15, rowA1 = rowA0 + 16;
    mfma_tileG(As, wW16 + (size_t)l * 4096, 64, 0, rowA0, rowA1, rowA0 & 7, rowA1 & 7, l15, lg, acc);
    int base = rb + w * 32;
    float m = -INFINITY;
#pragma unroll
    for (int rf = 0; rf < 2; ++rf)
#pragma unroll
        for (int q = 0; q < 4; ++q) {
            int r = base + rf * 16 + lg * 4 + q;
            if (r < n) {
                int c = clus[r];
                const float* mwr = MW + (size_t)c * 64;
#pragma unroll
                for (int nf = 0; nf < 4; ++nf) {
                    int col = nf * 16 + l15;
                    float v = acc[rf][nf][q] - mwr[col];
                    A[(size_t)r * 64 + col] = f2bf(v);   // in place: C over A
                    m = fmaxf(m, v);
                }
            }
        }
    __syncthreads();
    float* sp = (float*)As;
    sp[t] = m;
    __syncthreads();
    for (int s = 128; s > 0; s >>= 1) {
        if (t < s) sp[t] = fmaxf(sp[t], sp[t + s]);
        __syncthreads();
    }
    if (t == 0) atomicMax(&gmax[l], encf(sp[0]));
}

// ================= fused per-cluster softmax pool, all 3 levels in one dispatch =================
__global__ __launch_bounds__(256) void expf3_kernel(const ushort* __restrict__ C3, const ushort* __restrict__ E0,
                                                    const ushort* __restrict__ E1, const ushort* __restrict__ E2,
                                                    const double* __restrict__ stats,
                                                    const float* __restrict__ proj_g, const float* __restrict__ proj_b,
                                                    int n, const unsigned* __restrict__ gmax,
                                                    const int* __restrict__ cnts, const int* __restrict__ offs,
                                                    const int* __restrict__ perm, float* __restrict__ seg3) {
    int l = blockIdx.x >> 11, c = blockIdx.x & (KCL - 1);
    const ushort* C = C3 + (size_t)l * n * 64;
    const ushort* E = (l == 0) ? E0 : (l == 1) ? E1 : E2;
    __shared__ float sb[128];
    bn_sb(stats + (size_t)(2 * l + 1) * 128, proj_g + l * 64, proj_b + l * 64, n, sb);
    int t = threadIdx.x, col = t & 63, rg = t >> 6;
    float gm = decf(gmax[l]);
    int o = offs[l * KCL + c], m = cnts[l * KCL + c];
    float accd = 0.f, accn = 0.f;
    float sc = sb[col], bi = sb[64 + col];
    for (int j = rg; j < m; j += 4) {
        int row = perm[o + j];
        float d = expf(bf2f(C[(size_t)row * 64 + col]) - gm);
        float pf = lrelu(bf2f(E[(size_t)row * 64 + col]) * sc + bi);
        accd += d;
        accn += pf * d;
    }
    __shared__ float redd[256], redn[256];
    redd[t] = accd;
    redn[t] = accn;
    __syncthreads();
    if (t < 64) {
        float sd = redd[t] + redd[t + 64] + redd[t + 128] + redd[t + 192];
        float sn = redn[t] + redn[t + 64] + redn[t + 128] + redn[t + 192];
        seg3[(size_t)l * KCL * 64 + (size_t)c * 64 + col] = sn / (sd + 1e-6f);
    }
}

// ================= fuse GEMM: t3 = [bnlrelu(P3) | blend] @ Wf(128x64), bf16 out + stats =================
__global__ __launch_bounds__(256) void fuse_mfma(const ushort* __restrict__ P3, const double* __restrict__ statsP,
                                                 const float* __restrict__ gg, const float* __restrict__ bb, int n,
                                                 const float* __restrict__ adp, const int* __restrict__ clusters,
                                                 const float* __restrict__ s3_0, const float* __restrict__ s3_1,
                                                 const float* __restrict__ s3_2, const ushort* __restrict__ WfT,
                                                 ushort* __restrict__ out, double* __restrict__ stats_out) {
    __shared__ uint4 As[128 * 8];
    __shared__ float sb[128];
    int t = threadIdx.x, lane = t & 63, w = t >> 6;
    int rb = blockIdx.x * 128;
    int arow = t >> 1, ah = t & 1;
    const int l15 = lane & 15, lg = lane >> 4;

    bn_sb(statsP, gg, bb, n, sb);

    f4v acc[2][4];
#pragma unroll
    for (int rf = 0; rf < 2; ++rf)
#pragma unroll
        for (int nf = 0; nf < 4; ++nf)
#pragma unroll
            for (int q = 0; q < 4; ++q) acc[rf][nf][q] = 0.f;

    int rowA0 = w * 32 + l15, rowA1 = rowA0 + 16;
    int row = rb + arow;

    for (int p = 0; p < 2; ++p) {
        if (p) __syncthreads();
        float vals[32];
        if (row < n) {
            if (p == 0) {
                const U8* s8p = (const U8*)(P3 + (size_t)row * 64 + ah * 32);
#pragma unroll
                for (int c = 0; c < 4; ++c) {
                    U8 u = s8p[c];
#pragma unroll
                    for (int e = 0; e < 8; ++e) {
                        int col = ah * 32 + c * 8 + e;
                        vals[c * 8 + e] = lrelu(bf2f(u.u[e]) * sb[col] + sb[64 + col]);
                    }
                }
            } else {
                float a0 = adp[(size_t)row * 3 + 0], a1 = adp[(size_t)row * 3 + 1], a2 = adp[(size_t)row * 3 + 2];
                const float* r0 = s3_0 + (size_t)clusters[row] * 64 + ah * 32;
                const float* r1 = s3_1 + (size_t)clusters[(size_t)n + row] * 64 + ah * 32;
                const float* r2 = s3_2 + (size_t)clusters[2 * (size_t)n + row] * 64 + ah * 32;
#pragma unroll
                for (int i = 0; i < 32; ++i) vals[i] = a0 * r0[i] + a1 * r1[i] + a2 * r2[i];
            }
        } else {
#pragma unroll
            for (int i = 0; i < 32; ++i) vals[i] = 0.f;
        }
        stage_a_vals(vals, As, arow, ah);
        __syncthreads();
        mfma_tileG(As, WfT, 128, p * 64, rowA0, rowA1, rowA0 & 7, rowA1 & 7, l15, lg, acc);
    }
    int base = rb + w * 32;
#pragma unroll
    for (int rf = 0; rf < 2; ++rf)
#pragma unroll
        for (int nf = 0; nf < 4; ++nf)
#pragma unroll
            for (int q = 0; q < 4; ++q) {
                int r = base + rf * 16 + lg * 4 + q;
                if (r < n) out[(size_t)r * 64 + nf * 16 + l15] = f2bf(acc[rf][nf][q]);
            }
    __syncthreads();
    float* sp = (float*)As;
    int gidx = w * 4 + lg;
#pragma unroll
    for (int nf = 0; nf < 4; ++nf) {
        int col = nf * 16 + l15;
        float s = 0.f, s2 = 0.f;
#pragma unroll
        for (int rf = 0; rf < 2; ++rf)
#pragma unroll
            for (int q = 0; q < 4; ++q) {
                int r = base + rf * 16 + lg * 4 + q;
                if (r < n) {
                    float v = acc[rf][nf][q];
                    s += v;
                    s2 += v * v;
                }
            }
        sp[gidx * 64 + col] = s;
        sp[1024 + gidx * 64 + col] = s2;
    }
    __syncthreads();
    if (t < 64) {
        float s = 0.f, s2 = 0.f;
#pragma unroll
        for (int i = 0; i < 16; ++i) {
            s += sp[i * 64 + t];
            s2 += sp[1024 + i * 64 + t];
        }
        atomicAdd(&stats_out[t], (double)s);
        atomicAdd(&stats_out[64 + t], (double)s2);
    }
}

// ================= submanifold conv: A+W LDS double-buffered (r5) + zero-skip (r6) =================
__global__ __launch_bounds__(256) void subm_conv_db(const ushort* __restrict__ fin, const int* __restrict__ nbr,
                                                    const ushort* __restrict__ Wt, ushort* __restrict__ vout,
                                                    int n, double* __restrict__ stats_out) {
    __shared__ uint4 As[2][128 * 8];
    __shared__ uint4 Ws[2][64 * 8];
    int t = threadIdx.x;
    int lane = t & 63, w = t >> 6;
    int rb = blockIdx.x * 128;
    int arow = t >> 1, ah = t & 1;
    int wrow = t >> 2, wq = t & 3;
    const int l15 = lane & 15, lg = lane >> 4;
    int rowA0 = w * 32 + l15, rowA1 = rowA0 + 16;
    int swA0 = rowA0 & 7, swA1 = rowA1 & 7;
    const bool rowok = (rb + arow) < n;
    const int swa = arow & 7, sww = wrow & 7;

    f4v acc[2][4];
#pragma unroll
    for (int rf = 0; rf < 2; ++rf)
#pragma unroll
        for (int nf = 0; nf < 4; ++nf)
#pragma unroll
            for (int q = 0; q < 4; ++q) acc[rf][nf][q] = 0.f;

    // prologue: k=0 into buf0, prefetch nbr for k=1
    bool fc0, fc1, wzc, wzn = false;
    {
        int gi = rowok ? nbr[rb + arow] : -1;
        uint4 v0 = {0, 0, 0, 0}, v1 = v0, v2 = v0, v3 = v0;
        if (gi >= 0) {
            const uint4* src = (const uint4*)(fin + (size_t)gi * 64) + ah * 4;
            v0 = src[0]; v1 = src[1]; v2 = src[2]; v3 = src[3];
        }
        unsigned long long bal = __ballot(gi >= 0);
        fc0 = (bal & 0xffffffffull) != 0ull;
        fc1 = (bal >> 32) != 0ull;
        wzc = (gi < 0);
        uint4* dst = As[0] + arow * 8;
        dst[(ah * 4 + 0) ^ swa] = v0;
        dst[(ah * 4 + 1) ^ swa] = v1;
        dst[(ah * 4 + 2) ^ swa] = v2;
        dst[(ah * 4 + 3) ^ swa] = v3;
        const uint4* ws = (const uint4*)(Wt + (size_t)wrow * 64);
        uint4* wdst = Ws[0] + wrow * 8;
        wdst[wq ^ sww] = ws[wq];
        wdst[(wq + 4) ^ sww] = ws[wq + 4];
    }
    int gi_next = rowok ? nbr[(size_t)n + rb + arow] : -1;
    int cur = 0;

    for (int k = 0; k < 27; ++k) {
        uint4 a0, a1, a2, a3, w0, w1;
        bool fn0 = false, fn1 = false, missn = true;
        if (k < 26) {
            missn = (gi_next < 0);
            a0 = a1 = a2 = a3 = (uint4){0, 0, 0, 0};
            if (!missn) {
                const uint4* src = (const uint4*)(fin + (size_t)gi_next * 64) + ah * 4;
                a0 = src[0]; a1 = src[1]; a2 = src[2]; a3 = src[3];
            }
            unsigned long long bal = __ballot(!missn);
            fn0 = (bal & 0xffffffffull) != 0ull;
            fn1 = (bal >> 32) != 0ull;
            const uint4* ws = (const uint4*)(Wt + (size_t)(k + 1) * 4096 + (size_t)wrow * 64);
            w0 = ws[wq];
            w1 = ws[wq + 4];
            if (k < 25) gi_next = rowok ? nbr[(size_t)(k + 2) * n + rb + arow] : -1;
        }
        __syncthreads();
        if (fc0 | fc1) {
            const s8v* Av = (const s8v*)As[cur];
            const s8v* Wv = (const s8v*)Ws[cur];
#pragma unroll
            for (int kb = 0; kb < 2; ++kb) {
                int gch = kb * 4 + lg;
                s8v bfr[4];
#pragma unroll
                for (int nf = 0; nf < 4; ++nf) {
                    int col = nf * 16 + l15;
                    bfr[nf] = Wv[col * 8 + (gch ^ (col & 7))];
                }
                if (fc0) {
                    s8v av0 = Av[rowA0 * 8 + (gch ^ swA0)];
#pragma unroll
                    for (int nf = 0; nf < 4; ++nf)
                        acc[0][nf] = __builtin_amdgcn_mfma_f32_16x16x32_bf16(av0, bfr[nf], acc[0][nf], 0, 0, 0);
                }
                if (fc1) {
                    s8v av1 = Av[rowA1 * 8 + (gch ^ swA1)];
#pragma unroll
                    for (int nf = 0; nf < 4; ++nf)
                        acc[1][nf] = __builtin_amdgcn_mfma_f32_16x16x32_bf16(av1, bfr[nf], acc[1][nf], 0, 0, 0);
                }
            }
        }
        if (k < 26) {
            if (!(missn && wzn)) {   // skip rewrite if row already zero in target buffer
                uint4* dst = As[cur ^ 1] + arow * 8;
                dst[(ah * 4 + 0) ^ swa] = a0;
                dst[(ah * 4 + 1) ^ swa] = a1;
                dst[(ah * 4 + 2) ^ swa] = a2;
                dst[(ah * 4 + 3) ^ swa] = a3;
            }
            uint4* wdst = Ws[cur ^ 1] + wrow * 8;
            wdst[wq ^ sww] = w0;
            wdst[(wq + 4) ^ sww] = w1;
            cur ^= 1;
            bool nw = wzc;
            wzc = missn;
            wzn = nw;
            fc0 = fn0;
            fc1 = fn1;
        }
    }
    int base = rb + w * 32;
#pragma unroll
    for (int rf = 0; rf < 2; ++rf)
#pragma unroll
        for (int nf = 0; nf < 4; ++nf)
#pragma unroll
            for (int q = 0; q < 4; ++q) {
                int r = base + rf * 16 + lg * 4 + q;
                if (r < n) vout[(size_t)r * 64 + nf * 16 + l15] = f2bf(acc[rf][nf][q]);
            }
    __syncthreads();
    float* sp = (float*)As[0];
    int gidx = w * 4 + lg;
#pragma unroll
    for (int nf = 0; nf < 4; ++nf) {
        int col = nf * 16 + l15;
        float s = 0.f, s2 = 0.f;
#pragma unroll
        for (int rf = 0; rf < 2; ++rf)
#pragma unroll
            for (int q = 0; q < 4; ++q) {
                int r = base + rf * 16 + lg * 4 + q;
                if (r < n) {
                    float v = acc[rf][nf][q];
                    s += v;
                    s2 += v * v;
                }
            }
        sp[gidx * 64 + col] = s;
        sp[1024 + gidx * 64 + col] = s2;
    }
    __syncthreads();
    if (t < 64) {
        float s = 0.f, s2 = 0.f;
#pragma unroll
        for (int i = 0; i < 16; ++i) {
            s += sp[i * 64 + t];
            s2 += sp[1024 + i * 64 + t];
        }
        atomicAdd(&stats_out[t], (double)s);
        atomicAdd(&stats_out[64 + t], (double)s2);
    }
}

// ---------------- f16 = bf16(lrelu(bn(t3)) + feat) ----------------
__global__ __launch_bounds__(256) void addfeat_kernel(const ushort* __restrict__ t3, const double* __restrict__ stats,
                                                      const float* __restrict__ g, const float* __restrict__ b,
                                                      const float* __restrict__ feat, ushort* __restrict__ f16,
                                                      int n) {
    __shared__ float sb[128];
    bn_sb(stats, g, b, n, sb);
    long total4 = (long)n * 16;
    for (long i = (long)blockIdx.x * 256 + threadIdx.x; i < total4; i += (long)gridDim.x * 256) {
        int c0 = (int)(i & 15) * 4;
        ushort4 xv = ((const ushort4*)t3)[i];
        float4 fz = ((const float4*)feat)[i];
        ushort4 u;
        u.x = f2bf(lrelu(bf2f(xv.x) * sb[c0 + 0] + sb[64 + c0 + 0]) + fz.x);
        u.y = f2bf(lrelu(bf2f(xv.y) * sb[c0 + 1] + sb[64 + c0 + 1]) + fz.y);
        u.z = f2bf(lrelu(bf2f(xv.z) * sb[c0 + 2] + sb[64 + c0 + 2]) + fz.z);
        u.w = f2bf(lrelu(bf2f(xv.w) * sb[c0 + 3] + sb[64 + c0 + 3]) + fz.w);
        ((ushort4*)f16)[i] = u;
    }
}

// ---------------- o16 = bf16(lrelu(bn(v16))) ----------------
__global__ __launch_bounds__(256) void bnlrelu_tobf16_kernel(const ushort* __restrict__ v,
                                                             const double* __restrict__ stats,
                                                             const float* __restrict__ g, const float* __restrict__ b,
                                                             ushort* __restrict__ o16, int n) {
    __shared__ float sb[128];
    bn_sb(stats, g, b, n, sb);
    long total4 = (long)n * 16;
    for (long i = (long)blockIdx.x * 256 + threadIdx.x; i < total4; i += (long)gridDim.x * 256) {
        int c0 = (int)(i & 15) * 4;
        ushort4 xv = ((const ushort4*)v)[i];
        ushort4 u;
        u.x = f2bf(lrelu(bf2f(xv.x) * sb[c0 + 0] + sb[64 + c0 + 0]));
        u.y = f2bf(lrelu(bf2f(xv.y) * sb[c0 + 1] + sb[64 + c0 + 1]));
        u.z = f2bf(lrelu(bf2f(xv.z) * sb[c0 + 2] + sb[64 + c0 + 2]));
        u.w = f2bf(lrelu(bf2f(xv.w) * sb[c0 + 3] + sb[64 + c0 + 3]));
        ((ushort4*)o16)[i] = u;
    }
}

// ---------------- out = lrelu(bn(w16) + f16) ----------------
__global__ __launch_bounds__(256) void final_kernel(const ushort* __restrict__ w16, const double* __restrict__ stats,
                                                    const float* __restrict__ g, const float* __restrict__ b,
                                                    const ushort* __restrict__ f16, float* __restrict__ out, int n) {
    __shared__ float sb[128];
    bn_sb(stats, g, b, n, sb);
    long total4 = (long)n * 16;
    for (long i = (long)blockIdx.x * 256 + threadIdx.x; i < total4; i += (long)gridDim.x * 256) {
        int c0 = (int)(i & 15) * 4;
        ushort4 xv = ((const ushort4*)w16)[i];
        ushort4 u = ((const ushort4*)f16)[i];
        float4 y;
        y.x = lrelu(bf2f(xv.x) * sb[c0 + 0] + sb[64 + c0 + 0] + bf2f(u.x));
        y.y = lrelu(bf2f(xv.y) * sb[c0 + 1] + sb[64 + c0 + 1] + bf2f(u.y));
        y.z = lrelu(bf2f(xv.z) * sb[c0 + 2] + sb[64 + c0 + 2] + bf2f(u.z));
        y.w = lrelu(bf2f(xv.w) * sb[c0 + 3] + sb[64 + c0 + 3] + bf2f(u.w));
        ((float4*)out)[i] = y;
    }
}

extern "C" void kernel_launch(void* const* d_in, const int* in_sizes, int n_in,
                              void* d_out, int out_size, void* d_ws, size_t ws_size,
                              hipStream_t stream) {
    const float* feat = (const float*)d_in[0];
    const float* lw_W = (const float*)d_in[1];
    const float* lw_g = (const float*)d_in[2];
    const float* lw_b = (const float*)d_in[3];
    const float* w_W = (const float*)d_in[4];
    const float* proj_W = (const float*)d_in[5];
    const float* proj_g = (const float*)d_in[6];
    const float* proj_b = (const float*)d_in[7];
    const float* adaptive_W = (const float*)d_in[8];
    const float* fuse_W = (const float*)d_in[9];
    const float* fuse_g = (const float*)d_in[10];
    const float* fuse_b = (const float*)d_in[11];
    const float* conv1_W = (const float*)d_in[12];
    const float* bn1_g = (const float*)d_in[13];
    const float* bn1_b = (const float*)d_in[14];
    const float* conv2_W = (const float*)d_in[15];
    const float* bn2_g = (const float*)d_in[16];
    const float* bn2_b = (const float*)d_in[17];
    const int* clusters = (const int*)d_in[18];
    const int* nbr = (const int*)d_in[19];

    const int n = in_sizes[0] / 64;

    char* ws = (char*)d_ws;
    size_t off = 0;
    auto alloc = [&](size_t bytes) -> size_t {
        size_t o = off;
        off = (off + bytes + 255) & ~(size_t)255;
        return o;
    };
    // zeroed region
    size_t cnt_off = alloc((size_t)3 * KCL * 4);
    size_t stats_off = alloc((size_t)10 * 128 * 8);
    size_t gmax_off = alloc(16);
    size_t zbytes = off;
    // non-zeroed
    size_t offs_off = alloc((size_t)3 * KCL * 4);
    size_t cur_off = alloc((size_t)3 * KCL * 4);
    size_t perm_off = alloc((size_t)3 * n * 4);
    size_t mean_off = alloc((size_t)3 * KCL * 64 * 4);
    size_t mw_off = alloc((size_t)3 * KCL * 64 * 4);
    size_t seg3_off = alloc((size_t)3 * KCL * 64 * 4);
    size_t adp_off = alloc((size_t)n * 3 * 4);
    size_t feat16_off = alloc((size_t)n * 64 * 2);
    size_t ra_off = alloc((size_t)3 * n * 64 * 2);   // A0-2 (later C0-2 in place; later t3/fbuf16/c1out)
    size_t re_off = alloc((size_t)2 * n * 64 * 2);   // E0,E1 (later cbuf, c2out)
    size_t wt64_off = alloc((size_t)64 * 4096 * 2);
    size_t wfT_off = alloc((size_t)8192 * 2);

    int* cnts = (int*)(ws + cnt_off);
    double* stats = (double*)(ws + stats_off);
    unsigned* gmax = (unsigned*)(ws + gmax_off);
    int* offs = (int*)(ws + offs_off);
    int* cursor = (int*)(ws + cur_off);
    int* perm = (int*)(ws + perm_off);
    float* meanB3 = (float*)(ws + mean_off);
    float* MW3 = (float*)(ws + mw_off);
    float* seg3 = (float*)(ws + seg3_off);
    float* adp = (float*)(ws + adp_off);
    ushort* feat16 = (ushort*)(ws + feat16_off);
    ushort* RA = (ushort*)(ws + ra_off);
    ushort* RE = (ushort*)(ws + re_off);
    ushort* wt64 = (ushort*)(ws + wt64_off);
    ushort* wfT = (ushort*)(ws + wfT_off);
    float* outp = (float*)d_out;

    // buffer aliases (sequential liveness on one stream)
    ushort* A3 = RA;                                  // A0-2, then C0-2 in place
    ushort* E0 = RE;
    ushort* E1 = RE + (size_t)n * 64;
    ushort* E2 = (ushort*)d_out;                      // d_out low half as bf16 scratch
    ushort* P3 = (ushort*)d_out + (size_t)n * 64;     // d_out high half
    ushort* t3buf = RA;                               // after expf3 (A/C dead)
    ushort* fbuf16 = RA + (size_t)n * 64;
    ushort* c1out = RA + (size_t)2 * n * 64;
    ushort* cbuf = RE;                                // after expf3 (E0 dead)
    ushort* c2out = RE + (size_t)n * 64;              // (E1 dead)

    const ushort* wW16 = wt64 + (size_t)3 * 4096;
    const ushort* conv1W16 = wt64 + (size_t)10 * 4096;
    const ushort* conv2W16 = wt64 + (size_t)37 * 4096;

    hipMemsetAsync(d_ws, 0, zbytes, stream);

    const int GEMM_BLK = (n + 127) / 128;
    const int EW_BLK = 2048;

    prep_wt64<<<64, 256, 0, stream>>>(lw_W, w_W, proj_W, conv1_W, conv2_W, wt64);
    prep_fuse<<<1, 256, 0, stream>>>(fuse_W, wfT);
    adp_cvt_kernel<<<1024, 256, 0, stream>>>(feat, adaptive_W, adp, feat16, n);

    hist3_kernel<<<384, 256, 0, stream>>>(clusters, cnts, n);
    scan_kernel<<<3, 256, 0, stream>>>(cnts, offs, cursor, n);
    scatter_kernel<<<1024, 256, 0, stream>>>(clusters, cursor, perm, n);

    // A0-2 = feat16 @ lw_{0-2}; E0-2 = feat16 @ proj_{0-2}; P3 = feat16 @ proj_3 (+7 stats)
    mega7_gemm<<<GEMM_BLK, 256, 0, stream>>>(feat16, wt64,
                                             A3, A3 + (size_t)n * 64, A3 + (size_t)2 * n * 64,
                                             E0, E1, E2, P3, n, stats);
    // per-cluster means of bnlrelu(A_l)
    reduce_mean3_kernel<<<3 * KCL, 256, 0, stream>>>(A3, stats, lw_g, lw_b, n, cnts, offs, perm, meanB3);
    // MW_l = meanB_l @ wW_l
    mw3_gemm<<<3 * 16, 256, 0, stream>>>(meanB3, wW16, MW3);
    // C_l = bnlrelu(A_l) @ wW_l - MW_l[clus]  (in place over A_l) + gmax_l
    cgemm3<<<3 * GEMM_BLK, 256, 0, stream>>>(A3, wW16, MW3, clusters, stats, lw_g, lw_b, gmax, n, GEMM_BLK);
    // seg3_l[c] = Σ lrelu(bn(E))·exp(C-gmax) / (Σ exp(C-gmax)+1e-6), all levels
    expf3_kernel<<<3 * KCL, 256, 0, stream>>>(A3, E0, E1, E2, stats, proj_g, proj_b, n, gmax,
                                              cnts, offs, perm, seg3);

    // t3 = [bnlrelu(P3) | blend(adp,seg3)] @ fuse_W + stats(7)
    fuse_mfma<<<GEMM_BLK, 256, 0, stream>>>(P3, stats + 6 * 128, proj_g + 192, proj_b + 192, n,
                                            adp, clusters,
                                            seg3, seg3 + (size_t)KCL * 64, seg3 + (size_t)2 * KCL * 64,
                                            wfT, t3buf, stats + 7 * 128);
    // f = lrelu(bn(t3)) + feat  (bf16)
    addfeat_kernel<<<EW_BLK, 256, 0, stream>>>(t3buf, stats + 7 * 128, fuse_g, fuse_b, feat, fbuf16, n);

    // conv1 -> c1out (+stats 8); bn1+lrelu -> cbuf
    subm_conv_db<<<GEMM_BLK, 256, 0, stream>>>(fbuf16, nbr, conv1W16, c1out, n, stats + 8 * 128);
    bnlrelu_tobf16_kernel<<<EW_BLK, 256, 0, stream>>>(c1out, stats + 8 * 128, bn1_g, bn1_b, cbuf, n);

    // conv2 -> c2out (+stats 9); out = lrelu(bn2 + f)
    subm_conv_db<<<GEMM_BLK, 256, 0, stream>>>(cbuf, nbr, conv2W16, c2out, n, stats + 9 * 128);
    final_kernel<<<EW_BLK, 256, 0, stream>>>(c2out, stats + 9 * 128, bn2_g, bn2_b, fbuf16, outp, n);
}